// Round 6
// baseline (181.408 us; speedup 1.0000x reference)
//
#include <hip/hip_runtime.h>
#include <hip/hip_bf16.h>
#include <math.h>

// B=4, T=4096, C=1024, H=64 attention head, scores = K@Q^T, causal, softmax over s.
// R15 post-mortem: setprio attn = +6.5% as predicted (57->53.4us) but W-inline proj
// regressed ~+7us (scalar ds_write_b16 staging). R16 (this round): revert proj to
// the R9 vectorized-staging version (wtrans + Wt_g restored); keep setprio attn;
// Pb partial-slab stores made non-temporal (single-use, cross-XCD consumer -> keep
// them out of the local L2 that holds hot Q/V). 4 dispatches:
// wtrans -> proj -> attn -> reduce_norm.

typedef __attribute__((ext_vector_type(8))) short bf16x8;
typedef __attribute__((ext_vector_type(4))) short bf16x4;
typedef __attribute__((ext_vector_type(4))) float f32x4;

#define MFMA16(a, b, c) __builtin_amdgcn_mfma_f32_16x16x32_bf16(a, b, c, 0, 0, 0)

__device__ __forceinline__ short f2bf(float f) {
    union { float f; unsigned u; } v; v.f = f;
    unsigned r = v.u + 0x7FFFu + ((v.u >> 16) & 1u);   // RNE
    return (short)(r >> 16);
}

static constexpr int T = 4096;
static constexpr int C = 1024;
static constexpr int H = 64;
static constexpr int BATCH = 4;
static constexpr int M = BATCH * T;
static constexpr int CPB = 288;            // chunks per batch at CH=8 s-tiles/chunk
static constexpr float LOG2E = 1.44269504088896340736f;
static constexpr float KSCALE = 0.03125f * LOG2E;  // C^-0.5 * log2(e), folded into K

// ---------------------------------------------------------------------------
// Kernel 1: W -> bf16 transposed [192][1024] (LDS transpose). 48 blocks.
// ---------------------------------------------------------------------------
__global__ __launch_bounds__(256) void wtrans_kernel(
    const float* __restrict__ Wk, const float* __restrict__ Wq,
    const float* __restrict__ Wv, short* __restrict__ Wt_g)
{
    const int blk = blockIdx.x;
    const int tid = threadIdx.x;
    __shared__ short Wl[64][72];
    const int mat = blk / 16, k0 = (blk % 16) * 64;
    const float* W = (mat == 0) ? Wk : (mat == 1) ? Wq : Wv;
    const int hr = (tid & 15) * 4, kr = tid >> 4;
    #pragma unroll
    for (int pass = 0; pass < 4; ++pass) {
        int k = kr + pass * 16;
        float4 v = *(const float4*)&W[(size_t)(k0 + k) * H + hr];
        Wl[hr + 0][k] = f2bf(v.x);
        Wl[hr + 1][k] = f2bf(v.y);
        Wl[hr + 2][k] = f2bf(v.z);
        Wl[hr + 3][k] = f2bf(v.w);
    }
    __syncthreads();
    const int h = tid >> 2, kk = (tid & 3) * 16;
    bf16x8 o0 = *(const bf16x8*)&Wl[h][kk];
    bf16x8 o1 = *(const bf16x8*)&Wl[h][kk + 8];
    *(bf16x8*)&Wt_g[(size_t)(mat * 64 + h) * C + k0 + kk] = o0;
    *(bf16x8*)&Wt_g[(size_t)(mat * 64 + h) * C + k0 + kk + 8] = o1;
}

// ---------------------------------------------------------------------------
// Kernel 2: fused projection (R9 version), double-buffered LDS, one barrier
// per K-step. BM=64, BK=64, 512 threads. K pre-scaled. V tile-transposed.
// ---------------------------------------------------------------------------
__global__ __launch_bounds__(512) void proj_kernel(
    const float* __restrict__ x, const short* __restrict__ Wt_g,
    const float* __restrict__ bk, const float* __restrict__ bq,
    const float* __restrict__ bv,
    short* __restrict__ Kb, short* __restrict__ Qb, short* __restrict__ Vt)
{
    __shared__ short As[2][64][72];
    __shared__ short Ws[2][192][72];
    const int tid = threadIdx.x;
    const int wv = tid >> 6, lane = tid & 63, quad = lane >> 4, l16 = lane & 15;
    const int grp = wv >> 2, w4 = wv & 3;
    const int m0 = blockIdx.x * 64;
    const int arow = tid >> 3, ac8 = (tid & 7) * 8;

    f32x4 acc[6];
    #pragma unroll
    for (int i = 0; i < 6; ++i)
        for (int j = 0; j < 4; ++j) acc[i][j] = 0.f;

    float4 xa0, xa1;
    bf16x8 wl[3];
    auto gload = [&](int k0) {
        xa0 = *(const float4*)&x[(size_t)(m0 + arow) * C + k0 + ac8];
        xa1 = *(const float4*)&x[(size_t)(m0 + arow) * C + k0 + ac8 + 4];
        #pragma unroll
        for (int i = 0; i < 3; ++i) {
            int idx = tid + i * 512;
            wl[i] = *(const bf16x8*)&Wt_g[(size_t)(idx >> 3) * C + k0 + (idx & 7) * 8];
        }
    };
    auto lwrite = [&](int p) {
        bf16x8 av;
        av[0] = f2bf(xa0.x); av[1] = f2bf(xa0.y); av[2] = f2bf(xa0.z); av[3] = f2bf(xa0.w);
        av[4] = f2bf(xa1.x); av[5] = f2bf(xa1.y); av[6] = f2bf(xa1.z); av[7] = f2bf(xa1.w);
        *(bf16x8*)&As[p][arow][ac8] = av;
        #pragma unroll
        for (int i = 0; i < 3; ++i) {
            int idx = tid + i * 512;
            *(bf16x8*)&Ws[p][idx >> 3][(idx & 7) * 8] = wl[i];
        }
    };

    gload(0);
    lwrite(0);
    __syncthreads();
    for (int it = 0; it < 16; ++it) {
        const int p = it & 1;
        if (it < 15) gload((it + 1) * 64);
        bf16x8 a0 = *(const bf16x8*)&As[p][w4 * 16 + l16][quad * 8];
        bf16x8 a1 = *(const bf16x8*)&As[p][w4 * 16 + l16][32 + quad * 8];
        #pragma unroll
        for (int tn = 0; tn < 6; ++tn) {
            bf16x8 b0 = *(const bf16x8*)&Ws[p][grp * 96 + tn * 16 + l16][quad * 8];
            bf16x8 b1 = *(const bf16x8*)&Ws[p][grp * 96 + tn * 16 + l16][32 + quad * 8];
            acc[tn] = MFMA16(a0, b0, acc[tn]);
            acc[tn] = MFMA16(a1, b1, acc[tn]);
        }
        if (it < 15) {
            lwrite((it + 1) & 1);
            __syncthreads();
        }
    }
    #pragma unroll
    for (int tn = 0; tn < 6; ++tn) {
        int gc = grp * 96 + tn * 16 + l16;
        int mat = gc >> 6, h = gc & 63;
        const float* bias = (mat == 0) ? bk : (mat == 1) ? bq : bv;
        float bb = bias[h];
        float sc = (mat == 0) ? KSCALE : 1.f;
        #pragma unroll
        for (int r = 0; r < 4; ++r) {
            int row = m0 + w4 * 16 + quad * 4 + r;
            short val = f2bf((acc[tn][r] + bb) * sc);
            if (mat == 0)      Kb[(size_t)row * H + h] = val;
            else if (mat == 1) Qb[(size_t)row * H + h] = val;
            else               Vt[((size_t)(row >> 6)) * 4096 + h * 64 + (row & 63)] = val;
        }
    }
}

// ---------------------------------------------------------------------------
// chunk mapping (CH=8): t-tile tt has k = tt/8+1 chunks; group k (tiles
// 8(k-1)..8k-1) starts at c = 4k(k-1) and holds 8k chunks. Chunks of a tile
// are CONTIGUOUS: base_c(tt) = 4k(k-1) + (tt-8(k-1))*k.
// ---------------------------------------------------------------------------
__device__ __forceinline__ void chunk_map8(int c, int& tt, int& chunk) {
    int k = 1;
    while (c >= 4 * k * (k + 1)) ++k;          // k in [1,8]
    int off = c - 4 * k * (k - 1);
    int q = off / k;
    tt = 8 * (k - 1) + q;
    chunk = off - q * k;
}

// ---------------------------------------------------------------------------
// Kernel 3: flash attention partial (setprio around MFMA clusters).
// 4 waves/block (256 thr); wave = (sh, sp): strip-pair sp owns t-strips
// {2sp,2sp+1}; s-half sh takes even/odd s-tiles. s-halves merged in LDS.
// NO ATOMICS, NO FENCES. Partial slabs stored NON-TEMPORAL (single-use,
// consumed cross-XCD -> don't pollute local L2 holding hot Q/V).
// ---------------------------------------------------------------------------
__global__ __launch_bounds__(256) void attn_part_kernel(
    const short* __restrict__ Kb, const short* __restrict__ Qb,
    const short* __restrict__ Vt, float* __restrict__ Pb,
    float* __restrict__ lnPb)
{
    __shared__ short Pl[4][2][16][76];         // [wave][strip][t16][s]
    __shared__ float Ob[64][66];               // s-half merge buffer (padded)
    __shared__ float lnb[64];
    const int tid = threadIdx.x;
    const int wv = tid >> 6, lane = tid & 63;
    const int quad = lane >> 4, l16 = lane & 15;
    const int sp = wv & 1, sh = wv >> 1;       // strip-pair, s-half
    const int g = blockIdx.x;                  // 0..1151
    const int b = g & 3;                       // batch pinned per XCD
    const int c = CPB - 1 - (g >> 2);          // 0..287, heavy-first
    int tt, chunk;
    chunk_map8(c, tt, chunk);
    const int t0 = tt * 64;
    const int sA = sp * 2, sB = sp * 2 + 1;    // this wave's two strips
    const int st0 = chunk * 8;
    const int st1 = min(st0 + 8, tt + 1);
    const size_t base = (size_t)b * T * H;

    // K fragments (B operand, resident): B[k=h][n=t], lane l16 -> t-row
    const short* krA = Kb + base + (size_t)(t0 + sA * 16 + l16) * H;
    const short* krB = Kb + base + (size_t)(t0 + sB * 16 + l16) * H;
    bf16x8 kf0a = *(const bf16x8*)(krA + quad * 8);
    bf16x8 kf1a = *(const bf16x8*)(krA + 32 + quad * 8);
    bf16x8 kf0b = *(const bf16x8*)(krB + quad * 8);
    bf16x8 kf1b = *(const bf16x8*)(krB + 32 + quad * 8);

    bf16x8 ones;
    #pragma unroll
    for (int j = 0; j < 8; ++j) ones[j] = (short)0x3F80;   // bf16 1.0

    f32x4 oA[4], oB[4], lnA, lnB;
    #pragma unroll
    for (int i = 0; i < 4; ++i)
        for (int j = 0; j < 4; ++j) { oA[i][j] = 0.f; oB[i][j] = 0.f; }
    #pragma unroll
    for (int j = 0; j < 4; ++j) { lnA[j] = 0.f; lnB[j] = 0.f; }

    // this wave's s-tiles: st0+sh, st0+sh+2, ... (interleaved for balance)
    const int myb = st0 + sh;
    const short* qp = Qb + base + (size_t)(myb * 64 + l16) * H + quad * 8;
    const short* vp = Vt + ((size_t)(b * 64 + myb)) * 4096 + l16 * 64 + quad * 8;

    bf16x8 qc0[4], qc1[4];
    if (myb < st1) {
        #pragma unroll
        for (int tn = 0; tn < 4; ++tn) {
            qc0[tn] = *(const bf16x8*)(qp + tn * 1024);
            qc1[tn] = *(const bf16x8*)(qp + tn * 1024 + 32);
        }
    }

    for (int st = myb; st < st1; st += 2) {
        bf16x8 vb0[4], vb1[4];
        #pragma unroll
        for (int hn = 0; hn < 4; ++hn) {
            vb0[hn] = *(const bf16x8*)(vp + hn * 1024);
            vb1[hn] = *(const bf16x8*)(vp + hn * 1024 + 32);
        }
        // S^T for both strips: D[row=quad*4+r -> s][col=l16 -> t]
        f32x4 sAc[4], sBc[4];
        __builtin_amdgcn_s_setprio(1);
        #pragma unroll
        for (int tn = 0; tn < 4; ++tn) {
            #pragma unroll
            for (int j = 0; j < 4; ++j) { sAc[tn][j] = 0.f; sBc[tn][j] = 0.f; }
            sAc[tn] = MFMA16(qc0[tn], kf0a, sAc[tn]);
            sAc[tn] = MFMA16(qc1[tn], kf1a, sAc[tn]);
            sBc[tn] = MFMA16(qc0[tn], kf0b, sBc[tn]);
            sBc[tn] = MFMA16(qc1[tn], kf1b, sBc[tn]);
        }
        __builtin_amdgcn_s_setprio(0);
        // Q regs now dead -> load tile st+2's Q (covered by exp+LDS+PV below)
        const size_t qoff = (st + 2 < st1) ? 8192 : 0;
        #pragma unroll
        for (int tn = 0; tn < 4; ++tn) {
            qc0[tn] = *(const bf16x8*)(qp + qoff + tn * 1024);
            qc1[tn] = *(const bf16x8*)(qp + qoff + tn * 1024 + 32);
        }
        // p = exp2(s); mask only on the diagonal tile
        const bool diag = (st == tt);
        #pragma unroll
        for (int tn = 0; tn < 4; ++tn) {
            bf16x4 pa, pb;
            #pragma unroll
            for (int r = 0; r < 4; ++r) {
                float va = sAc[tn][r], vb = sBc[tn][r];
                if (diag) {
                    int scol = tn * 16 + quad * 4 + r;
                    if (scol > sA * 16 + l16) va = -INFINITY;
                    if (scol > sB * 16 + l16) vb = -INFINITY;
                }
                pa[r] = f2bf(exp2f(va));
                pb[r] = f2bf(exp2f(vb));
            }
            *(bf16x4*)&Pl[wv][0][l16][tn * 16 + quad * 4] = pa;
            *(bf16x4*)&Pl[wv][1][l16][tn * 16 + quad * 4] = pb;
        }
        // PV for both strips: A[m=t=l16][k=s] contiguous read-back
        bf16x8 aA0 = *(const bf16x8*)&Pl[wv][0][l16][quad * 8];
        bf16x8 aA1 = *(const bf16x8*)&Pl[wv][0][l16][32 + quad * 8];
        bf16x8 aB0 = *(const bf16x8*)&Pl[wv][1][l16][quad * 8];
        bf16x8 aB1 = *(const bf16x8*)&Pl[wv][1][l16][32 + quad * 8];
        __builtin_amdgcn_s_setprio(1);
        #pragma unroll
        for (int hn = 0; hn < 4; ++hn) {
            oA[hn] = MFMA16(aA0, vb0[hn], oA[hn]);
            oA[hn] = MFMA16(aA1, vb1[hn], oA[hn]);
            oB[hn] = MFMA16(aB0, vb0[hn], oB[hn]);
            oB[hn] = MFMA16(aB1, vb1[hn], oB[hn]);
        }
        lnA = MFMA16(aA0, ones, lnA);
        lnA = MFMA16(aA1, ones, lnA);
        lnB = MFMA16(aB0, ones, lnB);
        lnB = MFMA16(aB1, ones, lnB);
        __builtin_amdgcn_s_setprio(0);
        qp += 8192;
        vp += 8192;
    }

    // s-half merge: waves sh==1 stage partials in LDS; waves sh==0 add + store.
    const int rbase = sp * 32;
    if (sh == 1) {
        #pragma unroll
        for (int hn = 0; hn < 4; ++hn)
            #pragma unroll
            for (int r = 0; r < 4; ++r) {
                Ob[rbase + quad * 4 + r][hn * 16 + l16] = oA[hn][r];
                Ob[rbase + 16 + quad * 4 + r][hn * 16 + l16] = oB[hn][r];
            }
        if (l16 == 0) {
            #pragma unroll
            for (int r = 0; r < 4; ++r) {
                lnb[rbase + quad * 4 + r] = lnA[r];
                lnb[rbase + 16 + quad * 4 + r] = lnB[r];
            }
        }
    }
    __syncthreads();
    if (sh == 0) {
        float* Pc = Pb + (size_t)(b * CPB + c) * 4096;   // this chunk's 64x64 slab
        #pragma unroll
        for (int hn = 0; hn < 4; ++hn)
            #pragma unroll
            for (int r = 0; r < 4; ++r) {
                int ra = rbase + quad * 4 + r;
                int rb = ra + 16;
                float va = oA[hn][r] + Ob[ra][hn * 16 + l16];
                float vb = oB[hn][r] + Ob[rb][hn * 16 + l16];
                __builtin_nontemporal_store(va, &Pc[(size_t)ra * 64 + hn * 16 + l16]);
                __builtin_nontemporal_store(vb, &Pc[(size_t)rb * 64 + hn * 16 + l16]);
            }
        if (l16 == 0) {
            float* lc = lnPb + (size_t)(b * CPB + c) * 64;
            #pragma unroll
            for (int r = 0; r < 4; ++r) {
                lc[rbase + quad * 4 + r] = lnA[r] + lnb[rbase + quad * 4 + r];
                lc[rbase + 16 + quad * 4 + r] = lnB[r] + lnb[rbase + 16 + quad * 4 + r];
            }
        }
    }
}

// ---------------------------------------------------------------------------
// Kernel 4: reduce <=8 contiguous chunk partials per t-tile, normalize, write out.
// Grid: BATCH*64 blocks of 256 threads.
// ---------------------------------------------------------------------------
__global__ __launch_bounds__(256) void reduce_norm_kernel(
    const float* __restrict__ Pb, const float* __restrict__ lnPb,
    float* __restrict__ out)
{
    const int blk = blockIdx.x;                // b*64 + tt
    const int b = blk >> 6, tt = blk & 63;
    const int k = tt / 8 + 1;                  // number of chunk partials
    const int base_c = 4 * k * (k - 1) + (tt - 8 * (k - 1)) * k;
    const int tid = threadIdx.x;
    __shared__ float lnS[64];
    if (tid < 64) {
        float s = 0.f;
        for (int i = 0; i < k; ++i)
            s += lnPb[(size_t)(b * CPB + base_c + i) * 64 + tid];
        lnS[tid] = 1.f / s;
    }
    __syncthreads();
    float4 acc[4];
    #pragma unroll
    for (int j = 0; j < 4; ++j) acc[j] = {0.f, 0.f, 0.f, 0.f};
    for (int i = 0; i < k; ++i) {
        const float4* p4 = (const float4*)(Pb + (size_t)(b * CPB + base_c + i) * 4096);
        #pragma unroll
        for (int j = 0; j < 4; ++j) {
            float4 v = p4[tid + j * 256];
            acc[j].x += v.x; acc[j].y += v.y; acc[j].z += v.z; acc[j].w += v.w;
        }
    }
    float4* o4 = (float4*)out;
    const size_t obase = ((size_t)b * T + (size_t)tt * 64) * 16;   // float4 units
    #pragma unroll
    for (int j = 0; j < 4; ++j) {
        int idx = tid + j * 256;               // float4 index within 64x64 tile
        float inv = lnS[idx >> 4];             // 16 float4 per row
        float4 v = acc[j];
        v.x *= inv; v.y *= inv; v.z *= inv; v.w *= inv;
        o4[obase + idx] = v;
    }
}

// ---------------------------------------------------------------------------
extern "C" void kernel_launch(void* const* d_in, const int* in_sizes, int n_in,
                              void* d_out, int out_size, void* d_ws, size_t ws_size,
                              hipStream_t stream) {
    const float* x  = (const float*)d_in[0];
    const float* Wk = (const float*)d_in[1];
    const float* bk = (const float*)d_in[2];
    const float* Wq = (const float*)d_in[3];
    const float* bq = (const float*)d_in[4];
    const float* Wv = (const float*)d_in[5];
    const float* bv = (const float*)d_in[6];
    float* out = (float*)d_out;

    char* ws = (char*)d_ws;
    size_t off = 0;
    short* Kb   = (short*)(ws + off); off += (size_t)M * H * 2;            // 2 MB
    short* Qb   = (short*)(ws + off); off += (size_t)M * H * 2;            // 2 MB
    short* Vt   = (short*)(ws + off); off += (size_t)M * H * 2;            // 2 MB
    short* Wt_g = (short*)(ws + off); off += (size_t)192 * C * 2;          // 384 KB
    float* Pb   = (float*)(ws + off); off += (size_t)BATCH * CPB * 4096 * 4; // 18.9 MB
    float* lnPb = (float*)(ws + off); off += (size_t)BATCH * CPB * 64 * 4;   // 295 KB
    // total ~25.6 MB

    wtrans_kernel<<<48, 256, 0, stream>>>(Wk, Wq, Wv, Wt_g);
    proj_kernel<<<M / 64, 512, 0, stream>>>(x, Wt_g, bk, bq, bv, Kb, Qb, Vt);
    attn_part_kernel<<<BATCH * CPB, 256, 0, stream>>>(Kb, Qb, Vt, Pb, lnPb);
    reduce_norm_kernel<<<BATCH * 64, 256, 0, stream>>>(Pb, lnPb, out);
}

// Round 7
// 176.357 us; speedup vs baseline: 1.0286x; 1.0286x over previous
//
#include <hip/hip_runtime.h>
#include <hip/hip_bf16.h>
#include <math.h>

// B=4, T=4096, C=1024, H=64 attention head, scores = K@Q^T, causal, softmax over s.
// R16: nt stores neutral on attn, +7MB HBM write-through -> reverted. R17 (this
// round): VALU-issue diet. VALUBusy 23% at 13% occupancy implies ~800 VALU
// instr/step vs ~300 of real work. (1) exp2f was lowering to __ocml_exp2_f32
// (denormal guards, 10+ ops x32/step) -> __builtin_amdgcn_exp2f = bare v_exp_f32.
// (2) hand-rolled 4-op RNE f2bf -> native __float2bfloat16 (gfx950 lowers fptrunc
// to single v_cvt_pk_bf16_f32); same RNE numerics. Applies to attn P-pack (32/step)
// + proj staging/epilogue. Keep setprio attn, R9 proj, plain Pb stores, 4 dispatches.

typedef __attribute__((ext_vector_type(8))) short bf16x8;
typedef __attribute__((ext_vector_type(4))) short bf16x4;
typedef __attribute__((ext_vector_type(4))) float f32x4;

#define MFMA16(a, b, c) __builtin_amdgcn_mfma_f32_16x16x32_bf16(a, b, c, 0, 0, 0)

__device__ __forceinline__ short f2bf(float f) {
    __hip_bfloat16 h = __float2bfloat16(f);    // RNE; lowers to v_cvt_pk_bf16_f32
    return *reinterpret_cast<short*>(&h);
}

#if __has_builtin(__builtin_amdgcn_exp2f)
__device__ __forceinline__ float fexp2(float x) { return __builtin_amdgcn_exp2f(x); }
#else
__device__ __forceinline__ float fexp2(float x) { return exp2f(x); }
#endif

static constexpr int T = 4096;
static constexpr int C = 1024;
static constexpr int H = 64;
static constexpr int BATCH = 4;
static constexpr int M = BATCH * T;
static constexpr int CPB = 288;            // chunks per batch at CH=8 s-tiles/chunk
static constexpr float LOG2E = 1.44269504088896340736f;
static constexpr float KSCALE = 0.03125f * LOG2E;  // C^-0.5 * log2(e), folded into K

// ---------------------------------------------------------------------------
// Kernel 1: W -> bf16 transposed [192][1024] (LDS transpose). 48 blocks.
// ---------------------------------------------------------------------------
__global__ __launch_bounds__(256) void wtrans_kernel(
    const float* __restrict__ Wk, const float* __restrict__ Wq,
    const float* __restrict__ Wv, short* __restrict__ Wt_g)
{
    const int blk = blockIdx.x;
    const int tid = threadIdx.x;
    __shared__ short Wl[64][72];
    const int mat = blk / 16, k0 = (blk % 16) * 64;
    const float* W = (mat == 0) ? Wk : (mat == 1) ? Wq : Wv;
    const int hr = (tid & 15) * 4, kr = tid >> 4;
    #pragma unroll
    for (int pass = 0; pass < 4; ++pass) {
        int k = kr + pass * 16;
        float4 v = *(const float4*)&W[(size_t)(k0 + k) * H + hr];
        Wl[hr + 0][k] = f2bf(v.x);
        Wl[hr + 1][k] = f2bf(v.y);
        Wl[hr + 2][k] = f2bf(v.z);
        Wl[hr + 3][k] = f2bf(v.w);
    }
    __syncthreads();
    const int h = tid >> 2, kk = (tid & 3) * 16;
    bf16x8 o0 = *(const bf16x8*)&Wl[h][kk];
    bf16x8 o1 = *(const bf16x8*)&Wl[h][kk + 8];
    *(bf16x8*)&Wt_g[(size_t)(mat * 64 + h) * C + k0 + kk] = o0;
    *(bf16x8*)&Wt_g[(size_t)(mat * 64 + h) * C + k0 + kk + 8] = o1;
}

// ---------------------------------------------------------------------------
// Kernel 2: fused projection (R9 version), double-buffered LDS, one barrier
// per K-step. BM=64, BK=64, 512 threads. K pre-scaled. V tile-transposed.
// ---------------------------------------------------------------------------
__global__ __launch_bounds__(512) void proj_kernel(
    const float* __restrict__ x, const short* __restrict__ Wt_g,
    const float* __restrict__ bk, const float* __restrict__ bq,
    const float* __restrict__ bv,
    short* __restrict__ Kb, short* __restrict__ Qb, short* __restrict__ Vt)
{
    __shared__ short As[2][64][72];
    __shared__ short Ws[2][192][72];
    const int tid = threadIdx.x;
    const int wv = tid >> 6, lane = tid & 63, quad = lane >> 4, l16 = lane & 15;
    const int grp = wv >> 2, w4 = wv & 3;
    const int m0 = blockIdx.x * 64;
    const int arow = tid >> 3, ac8 = (tid & 7) * 8;

    f32x4 acc[6];
    #pragma unroll
    for (int i = 0; i < 6; ++i)
        for (int j = 0; j < 4; ++j) acc[i][j] = 0.f;

    float4 xa0, xa1;
    bf16x8 wl[3];
    auto gload = [&](int k0) {
        xa0 = *(const float4*)&x[(size_t)(m0 + arow) * C + k0 + ac8];
        xa1 = *(const float4*)&x[(size_t)(m0 + arow) * C + k0 + ac8 + 4];
        #pragma unroll
        for (int i = 0; i < 3; ++i) {
            int idx = tid + i * 512;
            wl[i] = *(const bf16x8*)&Wt_g[(size_t)(idx >> 3) * C + k0 + (idx & 7) * 8];
        }
    };
    auto lwrite = [&](int p) {
        bf16x8 av;
        av[0] = f2bf(xa0.x); av[1] = f2bf(xa0.y); av[2] = f2bf(xa0.z); av[3] = f2bf(xa0.w);
        av[4] = f2bf(xa1.x); av[5] = f2bf(xa1.y); av[6] = f2bf(xa1.z); av[7] = f2bf(xa1.w);
        *(bf16x8*)&As[p][arow][ac8] = av;
        #pragma unroll
        for (int i = 0; i < 3; ++i) {
            int idx = tid + i * 512;
            *(bf16x8*)&Ws[p][idx >> 3][(idx & 7) * 8] = wl[i];
        }
    };

    gload(0);
    lwrite(0);
    __syncthreads();
    for (int it = 0; it < 16; ++it) {
        const int p = it & 1;
        if (it < 15) gload((it + 1) * 64);
        bf16x8 a0 = *(const bf16x8*)&As[p][w4 * 16 + l16][quad * 8];
        bf16x8 a1 = *(const bf16x8*)&As[p][w4 * 16 + l16][32 + quad * 8];
        #pragma unroll
        for (int tn = 0; tn < 6; ++tn) {
            bf16x8 b0 = *(const bf16x8*)&Ws[p][grp * 96 + tn * 16 + l16][quad * 8];
            bf16x8 b1 = *(const bf16x8*)&Ws[p][grp * 96 + tn * 16 + l16][32 + quad * 8];
            acc[tn] = MFMA16(a0, b0, acc[tn]);
            acc[tn] = MFMA16(a1, b1, acc[tn]);
        }
        if (it < 15) {
            lwrite((it + 1) & 1);
            __syncthreads();
        }
    }
    #pragma unroll
    for (int tn = 0; tn < 6; ++tn) {
        int gc = grp * 96 + tn * 16 + l16;
        int mat = gc >> 6, h = gc & 63;
        const float* bias = (mat == 0) ? bk : (mat == 1) ? bq : bv;
        float bb = bias[h];
        float sc = (mat == 0) ? KSCALE : 1.f;
        #pragma unroll
        for (int r = 0; r < 4; ++r) {
            int row = m0 + w4 * 16 + quad * 4 + r;
            short val = f2bf((acc[tn][r] + bb) * sc);
            if (mat == 0)      Kb[(size_t)row * H + h] = val;
            else if (mat == 1) Qb[(size_t)row * H + h] = val;
            else               Vt[((size_t)(row >> 6)) * 4096 + h * 64 + (row & 63)] = val;
        }
    }
}

// ---------------------------------------------------------------------------
// chunk mapping (CH=8): t-tile tt has k = tt/8+1 chunks; group k (tiles
// 8(k-1)..8k-1) starts at c = 4k(k-1) and holds 8k chunks. Chunks of a tile
// are CONTIGUOUS: base_c(tt) = 4k(k-1) + (tt-8(k-1))*k.
// ---------------------------------------------------------------------------
__device__ __forceinline__ void chunk_map8(int c, int& tt, int& chunk) {
    int k = 1;
    while (c >= 4 * k * (k + 1)) ++k;          // k in [1,8]
    int off = c - 4 * k * (k - 1);
    int q = off / k;
    tt = 8 * (k - 1) + q;
    chunk = off - q * k;
}

// ---------------------------------------------------------------------------
// Kernel 3: flash attention partial (setprio around MFMA clusters; lean VALU:
// raw v_exp_f32 + native bf16 cvt). 4 waves/block; wave = (sh, sp).
// NO ATOMICS, NO FENCES. Plain coalesced partial-slab stores.
// ---------------------------------------------------------------------------
__global__ __launch_bounds__(256) void attn_part_kernel(
    const short* __restrict__ Kb, const short* __restrict__ Qb,
    const short* __restrict__ Vt, float* __restrict__ Pb,
    float* __restrict__ lnPb)
{
    __shared__ short Pl[4][2][16][76];         // [wave][strip][t16][s]
    __shared__ float Ob[64][66];               // s-half merge buffer (padded)
    __shared__ float lnb[64];
    const int tid = threadIdx.x;
    const int wv = tid >> 6, lane = tid & 63;
    const int quad = lane >> 4, l16 = lane & 15;
    const int sp = wv & 1, sh = wv >> 1;       // strip-pair, s-half
    const int g = blockIdx.x;                  // 0..1151
    const int b = g & 3;                       // batch pinned per XCD
    const int c = CPB - 1 - (g >> 2);          // 0..287, heavy-first
    int tt, chunk;
    chunk_map8(c, tt, chunk);
    const int t0 = tt * 64;
    const int sA = sp * 2, sB = sp * 2 + 1;    // this wave's two strips
    const int st0 = chunk * 8;
    const int st1 = min(st0 + 8, tt + 1);
    const size_t base = (size_t)b * T * H;

    // K fragments (B operand, resident): B[k=h][n=t], lane l16 -> t-row
    const short* krA = Kb + base + (size_t)(t0 + sA * 16 + l16) * H;
    const short* krB = Kb + base + (size_t)(t0 + sB * 16 + l16) * H;
    bf16x8 kf0a = *(const bf16x8*)(krA + quad * 8);
    bf16x8 kf1a = *(const bf16x8*)(krA + 32 + quad * 8);
    bf16x8 kf0b = *(const bf16x8*)(krB + quad * 8);
    bf16x8 kf1b = *(const bf16x8*)(krB + 32 + quad * 8);

    bf16x8 ones;
    #pragma unroll
    for (int j = 0; j < 8; ++j) ones[j] = (short)0x3F80;   // bf16 1.0

    f32x4 oA[4], oB[4], lnA, lnB;
    #pragma unroll
    for (int i = 0; i < 4; ++i)
        for (int j = 0; j < 4; ++j) { oA[i][j] = 0.f; oB[i][j] = 0.f; }
    #pragma unroll
    for (int j = 0; j < 4; ++j) { lnA[j] = 0.f; lnB[j] = 0.f; }

    // this wave's s-tiles: st0+sh, st0+sh+2, ... (interleaved for balance)
    const int myb = st0 + sh;
    const short* qp = Qb + base + (size_t)(myb * 64 + l16) * H + quad * 8;
    const short* vp = Vt + ((size_t)(b * 64 + myb)) * 4096 + l16 * 64 + quad * 8;

    bf16x8 qc0[4], qc1[4];
    if (myb < st1) {
        #pragma unroll
        for (int tn = 0; tn < 4; ++tn) {
            qc0[tn] = *(const bf16x8*)(qp + tn * 1024);
            qc1[tn] = *(const bf16x8*)(qp + tn * 1024 + 32);
        }
    }

    for (int st = myb; st < st1; st += 2) {
        bf16x8 vb0[4], vb1[4];
        #pragma unroll
        for (int hn = 0; hn < 4; ++hn) {
            vb0[hn] = *(const bf16x8*)(vp + hn * 1024);
            vb1[hn] = *(const bf16x8*)(vp + hn * 1024 + 32);
        }
        // S^T for both strips: D[row=quad*4+r -> s][col=l16 -> t]
        f32x4 sAc[4], sBc[4];
        __builtin_amdgcn_s_setprio(1);
        #pragma unroll
        for (int tn = 0; tn < 4; ++tn) {
            #pragma unroll
            for (int j = 0; j < 4; ++j) { sAc[tn][j] = 0.f; sBc[tn][j] = 0.f; }
            sAc[tn] = MFMA16(qc0[tn], kf0a, sAc[tn]);
            sAc[tn] = MFMA16(qc1[tn], kf1a, sAc[tn]);
            sBc[tn] = MFMA16(qc0[tn], kf0b, sBc[tn]);
            sBc[tn] = MFMA16(qc1[tn], kf1b, sBc[tn]);
        }
        __builtin_amdgcn_s_setprio(0);
        // Q regs now dead -> load tile st+2's Q (covered by exp+LDS+PV below)
        const size_t qoff = (st + 2 < st1) ? 8192 : 0;
        #pragma unroll
        for (int tn = 0; tn < 4; ++tn) {
            qc0[tn] = *(const bf16x8*)(qp + qoff + tn * 1024);
            qc1[tn] = *(const bf16x8*)(qp + qoff + tn * 1024 + 32);
        }
        // p = exp2(s); mask only on the diagonal tile
        const bool diag = (st == tt);
        #pragma unroll
        for (int tn = 0; tn < 4; ++tn) {
            bf16x4 pa, pb;
            #pragma unroll
            for (int r = 0; r < 4; ++r) {
                float va = sAc[tn][r], vb = sBc[tn][r];
                if (diag) {
                    int scol = tn * 16 + quad * 4 + r;
                    if (scol > sA * 16 + l16) va = -INFINITY;
                    if (scol > sB * 16 + l16) vb = -INFINITY;
                }
                pa[r] = f2bf(fexp2(va));
                pb[r] = f2bf(fexp2(vb));
            }
            *(bf16x4*)&Pl[wv][0][l16][tn * 16 + quad * 4] = pa;
            *(bf16x4*)&Pl[wv][1][l16][tn * 16 + quad * 4] = pb;
        }
        // PV for both strips: A[m=t=l16][k=s] contiguous read-back
        bf16x8 aA0 = *(const bf16x8*)&Pl[wv][0][l16][quad * 8];
        bf16x8 aA1 = *(const bf16x8*)&Pl[wv][0][l16][32 + quad * 8];
        bf16x8 aB0 = *(const bf16x8*)&Pl[wv][1][l16][quad * 8];
        bf16x8 aB1 = *(const bf16x8*)&Pl[wv][1][l16][32 + quad * 8];
        __builtin_amdgcn_s_setprio(1);
        #pragma unroll
        for (int hn = 0; hn < 4; ++hn) {
            oA[hn] = MFMA16(aA0, vb0[hn], oA[hn]);
            oA[hn] = MFMA16(aA1, vb1[hn], oA[hn]);
            oB[hn] = MFMA16(aB0, vb0[hn], oB[hn]);
            oB[hn] = MFMA16(aB1, vb1[hn], oB[hn]);
        }
        lnA = MFMA16(aA0, ones, lnA);
        lnA = MFMA16(aA1, ones, lnA);
        lnB = MFMA16(aB0, ones, lnB);
        lnB = MFMA16(aB1, ones, lnB);
        __builtin_amdgcn_s_setprio(0);
        qp += 8192;
        vp += 8192;
    }

    // s-half merge: waves sh==1 stage partials in LDS; waves sh==0 add + store.
    const int rbase = sp * 32;
    if (sh == 1) {
        #pragma unroll
        for (int hn = 0; hn < 4; ++hn)
            #pragma unroll
            for (int r = 0; r < 4; ++r) {
                Ob[rbase + quad * 4 + r][hn * 16 + l16] = oA[hn][r];
                Ob[rbase + 16 + quad * 4 + r][hn * 16 + l16] = oB[hn][r];
            }
        if (l16 == 0) {
            #pragma unroll
            for (int r = 0; r < 4; ++r) {
                lnb[rbase + quad * 4 + r] = lnA[r];
                lnb[rbase + 16 + quad * 4 + r] = lnB[r];
            }
        }
    }
    __syncthreads();
    if (sh == 0) {
        float* Pc = Pb + (size_t)(b * CPB + c) * 4096;   // this chunk's 64x64 slab
        #pragma unroll
        for (int hn = 0; hn < 4; ++hn)
            #pragma unroll
            for (int r = 0; r < 4; ++r) {
                int ra = rbase + quad * 4 + r;
                int rb = ra + 16;
                float va = oA[hn][r] + Ob[ra][hn * 16 + l16];
                float vb = oB[hn][r] + Ob[rb][hn * 16 + l16];
                Pc[(size_t)ra * 64 + hn * 16 + l16] = va;
                Pc[(size_t)rb * 64 + hn * 16 + l16] = vb;
            }
        if (l16 == 0) {
            float* lc = lnPb + (size_t)(b * CPB + c) * 64;
            #pragma unroll
            for (int r = 0; r < 4; ++r) {
                lc[rbase + quad * 4 + r] = lnA[r] + lnb[rbase + quad * 4 + r];
                lc[rbase + 16 + quad * 4 + r] = lnB[r] + lnb[rbase + 16 + quad * 4 + r];
            }
        }
    }
}

// ---------------------------------------------------------------------------
// Kernel 4: reduce <=8 contiguous chunk partials per t-tile, normalize, write out.
// Grid: BATCH*64 blocks of 256 threads.
// ---------------------------------------------------------------------------
__global__ __launch_bounds__(256) void reduce_norm_kernel(
    const float* __restrict__ Pb, const float* __restrict__ lnPb,
    float* __restrict__ out)
{
    const int blk = blockIdx.x;                // b*64 + tt
    const int b = blk >> 6, tt = blk & 63;
    const int k = tt / 8 + 1;                  // number of chunk partials
    const int base_c = 4 * k * (k - 1) + (tt - 8 * (k - 1)) * k;
    const int tid = threadIdx.x;
    __shared__ float lnS[64];
    if (tid < 64) {
        float s = 0.f;
        for (int i = 0; i < k; ++i)
            s += lnPb[(size_t)(b * CPB + base_c + i) * 64 + tid];
        lnS[tid] = 1.f / s;
    }
    __syncthreads();
    float4 acc[4];
    #pragma unroll
    for (int j = 0; j < 4; ++j) acc[j] = {0.f, 0.f, 0.f, 0.f};
    for (int i = 0; i < k; ++i) {
        const float4* p4 = (const float4*)(Pb + (size_t)(b * CPB + base_c + i) * 4096);
        #pragma unroll
        for (int j = 0; j < 4; ++j) {
            float4 v = p4[tid + j * 256];
            acc[j].x += v.x; acc[j].y += v.y; acc[j].z += v.z; acc[j].w += v.w;
        }
    }
    float4* o4 = (float4*)out;
    const size_t obase = ((size_t)b * T + (size_t)tt * 64) * 16;   // float4 units
    #pragma unroll
    for (int j = 0; j < 4; ++j) {
        int idx = tid + j * 256;               // float4 index within 64x64 tile
        float inv = lnS[idx >> 4];             // 16 float4 per row
        float4 v = acc[j];
        v.x *= inv; v.y *= inv; v.z *= inv; v.w *= inv;
        o4[obase + idx] = v;
    }
}

// ---------------------------------------------------------------------------
extern "C" void kernel_launch(void* const* d_in, const int* in_sizes, int n_in,
                              void* d_out, int out_size, void* d_ws, size_t ws_size,
                              hipStream_t stream) {
    const float* x  = (const float*)d_in[0];
    const float* Wk = (const float*)d_in[1];
    const float* bk = (const float*)d_in[2];
    const float* Wq = (const float*)d_in[3];
    const float* bq = (const float*)d_in[4];
    const float* Wv = (const float*)d_in[5];
    const float* bv = (const float*)d_in[6];
    float* out = (float*)d_out;

    char* ws = (char*)d_ws;
    size_t off = 0;
    short* Kb   = (short*)(ws + off); off += (size_t)M * H * 2;            // 2 MB
    short* Qb   = (short*)(ws + off); off += (size_t)M * H * 2;            // 2 MB
    short* Vt   = (short*)(ws + off); off += (size_t)M * H * 2;            // 2 MB
    short* Wt_g = (short*)(ws + off); off += (size_t)192 * C * 2;          // 384 KB
    float* Pb   = (float*)(ws + off); off += (size_t)BATCH * CPB * 4096 * 4; // 18.9 MB
    float* lnPb = (float*)(ws + off); off += (size_t)BATCH * CPB * 64 * 4;   // 295 KB
    // total ~25.6 MB

    wtrans_kernel<<<48, 256, 0, stream>>>(Wk, Wq, Wv, Wt_g);
    proj_kernel<<<M / 64, 512, 0, stream>>>(x, Wt_g, bk, bq, bv, Kb, Qb, Vt);
    attn_part_kernel<<<BATCH * CPB, 256, 0, stream>>>(Kb, Qb, Vt, Pb, lnPb);
    reduce_norm_kernel<<<BATCH * 64, 256, 0, stream>>>(Pb, lnPb, out);
}

// Round 8
// 149.339 us; speedup vs baseline: 1.2147x; 1.1809x over previous
//
#include <hip/hip_runtime.h>
#include <hip/hip_bf16.h>
#include <math.h>

// B=4, T=4096, C=1024, H=64 attention head, scores = K@Q^T, causal, softmax over s.
// R17 post-mortem: VALUBusy 23->15% but attn time FLAT -> VALU exonerated. All
// counted pipes idle at ~7K cyc/iteration -> suspect the UNCOUNTED per-CU TA/TCP
// request pipe: every attn global load is 16B/lane at 128B lane-stride (16 lines
// per wave-load). R18 (this round): FRAGMENT-NATIVE K/Q/V STORAGE. proj's scatter
// epilogue now writes MFMA fragment order X[tile][sub16][half][lane][8] so every
// attn K/Q/V load is a contiguous lane*16B 1KB burst (4 lines, minimal TA).
// Explains all prior invariances (TA is per-CU shared; R12 TLP x2, R13 atomics,
// R17 VALU diet all flat). Keep setprio, raw v_exp, native cvt, 4 dispatches.

typedef __attribute__((ext_vector_type(8))) short bf16x8;
typedef __attribute__((ext_vector_type(4))) short bf16x4;
typedef __attribute__((ext_vector_type(4))) float f32x4;

#define MFMA16(a, b, c) __builtin_amdgcn_mfma_f32_16x16x32_bf16(a, b, c, 0, 0, 0)

__device__ __forceinline__ short f2bf(float f) {
    __hip_bfloat16 h = __float2bfloat16(f);    // RNE; lowers to v_cvt_pk_bf16_f32
    return *reinterpret_cast<short*>(&h);
}

#if __has_builtin(__builtin_amdgcn_exp2f)
__device__ __forceinline__ float fexp2(float x) { return __builtin_amdgcn_exp2f(x); }
#else
__device__ __forceinline__ float fexp2(float x) { return exp2f(x); }
#endif

static constexpr int T = 4096;
static constexpr int C = 1024;
static constexpr int H = 64;
static constexpr int BATCH = 4;
static constexpr int M = BATCH * T;
static constexpr int CPB = 288;            // chunks per batch at CH=8 s-tiles/chunk
static constexpr float LOG2E = 1.44269504088896340736f;
static constexpr float KSCALE = 0.03125f * LOG2E;  // C^-0.5 * log2(e), folded into K

// Fragment layout per 64x64 tile (4096 shorts): off = sub16*1024 + half*512 +
// lane*8 + j. For K/Q: sub16 = row/16 (t or s), (half,j) from col h; lane =
// ((h&31)>>3)*16 + (row&15). For V (transposed roles): sub16 = h/16, (half,j)
// from s; lane = ((s&31)>>3)*16 + (h&15). Every attn load = base + lane*16B.

// ---------------------------------------------------------------------------
// Kernel 1: W -> bf16 transposed [192][1024] (LDS transpose). 48 blocks.
// ---------------------------------------------------------------------------
__global__ __launch_bounds__(256) void wtrans_kernel(
    const float* __restrict__ Wk, const float* __restrict__ Wq,
    const float* __restrict__ Wv, short* __restrict__ Wt_g)
{
    const int blk = blockIdx.x;
    const int tid = threadIdx.x;
    __shared__ short Wl[64][72];
    const int mat = blk / 16, k0 = (blk % 16) * 64;
    const float* W = (mat == 0) ? Wk : (mat == 1) ? Wq : Wv;
    const int hr = (tid & 15) * 4, kr = tid >> 4;
    #pragma unroll
    for (int pass = 0; pass < 4; ++pass) {
        int k = kr + pass * 16;
        float4 v = *(const float4*)&W[(size_t)(k0 + k) * H + hr];
        Wl[hr + 0][k] = f2bf(v.x);
        Wl[hr + 1][k] = f2bf(v.y);
        Wl[hr + 2][k] = f2bf(v.z);
        Wl[hr + 3][k] = f2bf(v.w);
    }
    __syncthreads();
    const int h = tid >> 2, kk = (tid & 3) * 16;
    bf16x8 o0 = *(const bf16x8*)&Wl[h][kk];
    bf16x8 o1 = *(const bf16x8*)&Wl[h][kk + 8];
    *(bf16x8*)&Wt_g[(size_t)(mat * 64 + h) * C + k0 + kk] = o0;
    *(bf16x8*)&Wt_g[(size_t)(mat * 64 + h) * C + k0 + kk + 8] = o1;
}

// ---------------------------------------------------------------------------
// Kernel 2: fused projection (R9 core), double-buffered LDS, one barrier per
// K-step. BM=64, BK=64, 512 threads. K pre-scaled. Epilogue scatters into
// FRAGMENT-NATIVE layout for K/Q/V (see map above).
// ---------------------------------------------------------------------------
__global__ __launch_bounds__(512) void proj_kernel(
    const float* __restrict__ x, const short* __restrict__ Wt_g,
    const float* __restrict__ bk, const float* __restrict__ bq,
    const float* __restrict__ bv,
    short* __restrict__ Kf, short* __restrict__ Qf, short* __restrict__ Vf)
{
    __shared__ short As[2][64][72];
    __shared__ short Ws[2][192][72];
    const int tid = threadIdx.x;
    const int wv = tid >> 6, lane = tid & 63, quad = lane >> 4, l16 = lane & 15;
    const int grp = wv >> 2, w4 = wv & 3;
    const int m0 = blockIdx.x * 64;
    const int arow = tid >> 3, ac8 = (tid & 7) * 8;

    f32x4 acc[6];
    #pragma unroll
    for (int i = 0; i < 6; ++i)
        for (int j = 0; j < 4; ++j) acc[i][j] = 0.f;

    float4 xa0, xa1;
    bf16x8 wl[3];
    auto gload = [&](int k0) {
        xa0 = *(const float4*)&x[(size_t)(m0 + arow) * C + k0 + ac8];
        xa1 = *(const float4*)&x[(size_t)(m0 + arow) * C + k0 + ac8 + 4];
        #pragma unroll
        for (int i = 0; i < 3; ++i) {
            int idx = tid + i * 512;
            wl[i] = *(const bf16x8*)&Wt_g[(size_t)(idx >> 3) * C + k0 + (idx & 7) * 8];
        }
    };
    auto lwrite = [&](int p) {
        bf16x8 av;
        av[0] = f2bf(xa0.x); av[1] = f2bf(xa0.y); av[2] = f2bf(xa0.z); av[3] = f2bf(xa0.w);
        av[4] = f2bf(xa1.x); av[5] = f2bf(xa1.y); av[6] = f2bf(xa1.z); av[7] = f2bf(xa1.w);
        *(bf16x8*)&As[p][arow][ac8] = av;
        #pragma unroll
        for (int i = 0; i < 3; ++i) {
            int idx = tid + i * 512;
            *(bf16x8*)&Ws[p][idx >> 3][(idx & 7) * 8] = wl[i];
        }
    };

    gload(0);
    lwrite(0);
    __syncthreads();
    for (int it = 0; it < 16; ++it) {
        const int p = it & 1;
        if (it < 15) gload((it + 1) * 64);
        bf16x8 a0 = *(const bf16x8*)&As[p][w4 * 16 + l16][quad * 8];
        bf16x8 a1 = *(const bf16x8*)&As[p][w4 * 16 + l16][32 + quad * 8];
        #pragma unroll
        for (int tn = 0; tn < 6; ++tn) {
            bf16x8 b0 = *(const bf16x8*)&Ws[p][grp * 96 + tn * 16 + l16][quad * 8];
            bf16x8 b1 = *(const bf16x8*)&Ws[p][grp * 96 + tn * 16 + l16][32 + quad * 8];
            acc[tn] = MFMA16(a0, b0, acc[tn]);
            acc[tn] = MFMA16(a1, b1, acc[tn]);
        }
        if (it < 15) {
            lwrite((it + 1) & 1);
            __syncthreads();
        }
    }
    #pragma unroll
    for (int tn = 0; tn < 6; ++tn) {
        int gc = grp * 96 + tn * 16 + l16;
        int mat = gc >> 6, h = gc & 63;
        const float* bias = (mat == 0) ? bk : (mat == 1) ? bq : bv;
        float bb = bias[h];
        float sc = (mat == 0) ? KSCALE : 1.f;
        // fragment coords from h (K/Q path)
        const int half = h >> 5, q = (h & 31) >> 3, j = h & 7;
        const int hn = h >> 4, l16f = h & 15;          // V path
        #pragma unroll
        for (int r = 0; r < 4; ++r) {
            int row = m0 + w4 * 16 + quad * 4 + r;
            short val = f2bf((acc[tn][r] + bb) * sc);
            int tile = row >> 6, s = row & 63;
            if (mat == 2) {
                int vhalf = s >> 5, vq = (s & 31) >> 3, vj = s & 7;
                Vf[(size_t)tile * 4096 + hn * 1024 + vhalf * 512
                   + (vq * 16 + l16f) * 8 + vj] = val;
            } else {
                int sub = s >> 4, sl16 = s & 15;
                size_t o = (size_t)tile * 4096 + sub * 1024 + half * 512
                           + (q * 16 + sl16) * 8 + j;
                if (mat == 0) Kf[o] = val;
                else          Qf[o] = val;
            }
        }
    }
}

// ---------------------------------------------------------------------------
// chunk mapping (CH=8): t-tile tt has k = tt/8+1 chunks; group k (tiles
// 8(k-1)..8k-1) starts at c = 4k(k-1) and holds 8k chunks. Chunks of a tile
// are CONTIGUOUS: base_c(tt) = 4k(k-1) + (tt-8(k-1))*k.
// ---------------------------------------------------------------------------
__device__ __forceinline__ void chunk_map8(int c, int& tt, int& chunk) {
    int k = 1;
    while (c >= 4 * k * (k + 1)) ++k;          // k in [1,8]
    int off = c - 4 * k * (k - 1);
    int q = off / k;
    tt = 8 * (k - 1) + q;
    chunk = off - q * k;
}

// ---------------------------------------------------------------------------
// Kernel 3: flash attention partial. Fragment-native K/Q/V: every global load
// is a contiguous lane*16B 1KB burst. setprio around MFMA clusters. 4 waves/
// block; wave = (sh, sp). NO ATOMICS, NO FENCES.
// ---------------------------------------------------------------------------
__global__ __launch_bounds__(256) void attn_part_kernel(
    const short* __restrict__ Kf, const short* __restrict__ Qf,
    const short* __restrict__ Vf, float* __restrict__ Pb,
    float* __restrict__ lnPb)
{
    __shared__ short Pl[4][2][16][76];         // [wave][strip][t16][s]
    __shared__ float Ob[64][66];               // s-half merge buffer (padded)
    __shared__ float lnb[64];
    const int tid = threadIdx.x;
    const int wv = tid >> 6, lane = tid & 63;
    const int quad = lane >> 4, l16 = lane & 15;
    const int sp = wv & 1, sh = wv >> 1;       // strip-pair, s-half
    const int g = blockIdx.x;                  // 0..1151
    const int b = g & 3;                       // batch pinned per XCD
    const int c = CPB - 1 - (g >> 2);          // 0..287, heavy-first
    int tt, chunk;
    chunk_map8(c, tt, chunk);
    const int t0 = tt * 64;
    const int sA = sp * 2, sB = sp * 2 + 1;    // this wave's two strips (t-sub16s)
    const int st0 = chunk * 8;
    const int st1 = min(st0 + 8, tt + 1);

    // K fragments: contiguous 1KB bursts at lane*8 shorts
    const short* kt = Kf + (size_t)(b * 64 + tt) * 4096 + lane * 8;
    bf16x8 kf0a = *(const bf16x8*)(kt + sA * 1024);
    bf16x8 kf1a = *(const bf16x8*)(kt + sA * 1024 + 512);
    bf16x8 kf0b = *(const bf16x8*)(kt + sB * 1024);
    bf16x8 kf1b = *(const bf16x8*)(kt + sB * 1024 + 512);

    bf16x8 ones;
    #pragma unroll
    for (int j = 0; j < 8; ++j) ones[j] = (short)0x3F80;   // bf16 1.0

    f32x4 oA[4], oB[4], lnA, lnB;
    #pragma unroll
    for (int i = 0; i < 4; ++i)
        for (int j = 0; j < 4; ++j) { oA[i][j] = 0.f; oB[i][j] = 0.f; }
    #pragma unroll
    for (int j = 0; j < 4; ++j) { lnA[j] = 0.f; lnB[j] = 0.f; }

    // this wave's s-tiles: st0+sh, st0+sh+2, ... (interleaved for balance)
    const int myb = st0 + sh;
    const short* qp = Qf + (size_t)(b * 64 + myb) * 4096 + lane * 8;
    const short* vp = Vf + (size_t)(b * 64 + myb) * 4096 + lane * 8;

    bf16x8 qc0[4], qc1[4];
    if (myb < st1) {
        #pragma unroll
        for (int tn = 0; tn < 4; ++tn) {
            qc0[tn] = *(const bf16x8*)(qp + tn * 1024);
            qc1[tn] = *(const bf16x8*)(qp + tn * 1024 + 512);
        }
    }

    for (int st = myb; st < st1; st += 2) {
        bf16x8 vb0[4], vb1[4];
        #pragma unroll
        for (int hn = 0; hn < 4; ++hn) {
            vb0[hn] = *(const bf16x8*)(vp + hn * 1024);
            vb1[hn] = *(const bf16x8*)(vp + hn * 1024 + 512);
        }
        // S^T for both strips: D[row=quad*4+r -> s][col=l16 -> t]
        f32x4 sAc[4], sBc[4];
        __builtin_amdgcn_s_setprio(1);
        #pragma unroll
        for (int tn = 0; tn < 4; ++tn) {
            #pragma unroll
            for (int j = 0; j < 4; ++j) { sAc[tn][j] = 0.f; sBc[tn][j] = 0.f; }
            sAc[tn] = MFMA16(qc0[tn], kf0a, sAc[tn]);
            sAc[tn] = MFMA16(qc1[tn], kf1a, sAc[tn]);
            sBc[tn] = MFMA16(qc0[tn], kf0b, sBc[tn]);
            sBc[tn] = MFMA16(qc1[tn], kf1b, sBc[tn]);
        }
        __builtin_amdgcn_s_setprio(0);
        // Q regs now dead -> load tile st+2's Q (covered by exp+LDS+PV below)
        const size_t qoff = (st + 2 < st1) ? 8192 : 0;
        #pragma unroll
        for (int tn = 0; tn < 4; ++tn) {
            qc0[tn] = *(const bf16x8*)(qp + qoff + tn * 1024);
            qc1[tn] = *(const bf16x8*)(qp + qoff + tn * 1024 + 512);
        }
        // p = exp2(s); mask only on the diagonal tile
        const bool diag = (st == tt);
        #pragma unroll
        for (int tn = 0; tn < 4; ++tn) {
            bf16x4 pa, pb;
            #pragma unroll
            for (int r = 0; r < 4; ++r) {
                float va = sAc[tn][r], vb = sBc[tn][r];
                if (diag) {
                    int scol = tn * 16 + quad * 4 + r;
                    if (scol > sA * 16 + l16) va = -INFINITY;
                    if (scol > sB * 16 + l16) vb = -INFINITY;
                }
                pa[r] = f2bf(fexp2(va));
                pb[r] = f2bf(fexp2(vb));
            }
            *(bf16x4*)&Pl[wv][0][l16][tn * 16 + quad * 4] = pa;
            *(bf16x4*)&Pl[wv][1][l16][tn * 16 + quad * 4] = pb;
        }
        // PV for both strips: A[m=t=l16][k=s] contiguous read-back
        bf16x8 aA0 = *(const bf16x8*)&Pl[wv][0][l16][quad * 8];
        bf16x8 aA1 = *(const bf16x8*)&Pl[wv][0][l16][32 + quad * 8];
        bf16x8 aB0 = *(const bf16x8*)&Pl[wv][1][l16][quad * 8];
        bf16x8 aB1 = *(const bf16x8*)&Pl[wv][1][l16][32 + quad * 8];
        __builtin_amdgcn_s_setprio(1);
        #pragma unroll
        for (int hn = 0; hn < 4; ++hn) {
            oA[hn] = MFMA16(aA0, vb0[hn], oA[hn]);
            oA[hn] = MFMA16(aA1, vb1[hn], oA[hn]);
            oB[hn] = MFMA16(aB0, vb0[hn], oB[hn]);
            oB[hn] = MFMA16(aB1, vb1[hn], oB[hn]);
        }
        lnA = MFMA16(aA0, ones, lnA);
        lnA = MFMA16(aA1, ones, lnA);
        lnB = MFMA16(aB0, ones, lnB);
        lnB = MFMA16(aB1, ones, lnB);
        __builtin_amdgcn_s_setprio(0);
        qp += 8192;
        vp += 8192;
    }

    // s-half merge: waves sh==1 stage partials in LDS; waves sh==0 add + store.
    const int rbase = sp * 32;
    if (sh == 1) {
        #pragma unroll
        for (int hn = 0; hn < 4; ++hn)
            #pragma unroll
            for (int r = 0; r < 4; ++r) {
                Ob[rbase + quad * 4 + r][hn * 16 + l16] = oA[hn][r];
                Ob[rbase + 16 + quad * 4 + r][hn * 16 + l16] = oB[hn][r];
            }
        if (l16 == 0) {
            #pragma unroll
            for (int r = 0; r < 4; ++r) {
                lnb[rbase + quad * 4 + r] = lnA[r];
                lnb[rbase + 16 + quad * 4 + r] = lnB[r];
            }
        }
    }
    __syncthreads();
    if (sh == 0) {
        float* Pc = Pb + (size_t)(b * CPB + c) * 4096;   // this chunk's 64x64 slab
        #pragma unroll
        for (int hn = 0; hn < 4; ++hn)
            #pragma unroll
            for (int r = 0; r < 4; ++r) {
                int ra = rbase + quad * 4 + r;
                int rb = ra + 16;
                float va = oA[hn][r] + Ob[ra][hn * 16 + l16];
                float vb = oB[hn][r] + Ob[rb][hn * 16 + l16];
                Pc[(size_t)ra * 64 + hn * 16 + l16] = va;
                Pc[(size_t)rb * 64 + hn * 16 + l16] = vb;
            }
        if (l16 == 0) {
            float* lc = lnPb + (size_t)(b * CPB + c) * 64;
            #pragma unroll
            for (int r = 0; r < 4; ++r) {
                lc[rbase + quad * 4 + r] = lnA[r] + lnb[rbase + quad * 4 + r];
                lc[rbase + 16 + quad * 4 + r] = lnB[r] + lnb[rbase + 16 + quad * 4 + r];
            }
        }
    }
}

// ---------------------------------------------------------------------------
// Kernel 4: reduce <=8 contiguous chunk partials per t-tile, normalize, write out.
// Grid: BATCH*64 blocks of 256 threads.
// ---------------------------------------------------------------------------
__global__ __launch_bounds__(256) void reduce_norm_kernel(
    const float* __restrict__ Pb, const float* __restrict__ lnPb,
    float* __restrict__ out)
{
    const int blk = blockIdx.x;                // b*64 + tt
    const int b = blk >> 6, tt = blk & 63;
    const int k = tt / 8 + 1;                  // number of chunk partials
    const int base_c = 4 * k * (k - 1) + (tt - 8 * (k - 1)) * k;
    const int tid = threadIdx.x;
    __shared__ float lnS[64];
    if (tid < 64) {
        float s = 0.f;
        for (int i = 0; i < k; ++i)
            s += lnPb[(size_t)(b * CPB + base_c + i) * 64 + tid];
        lnS[tid] = 1.f / s;
    }
    __syncthreads();
    float4 acc[4];
    #pragma unroll
    for (int j = 0; j < 4; ++j) acc[j] = {0.f, 0.f, 0.f, 0.f};
    for (int i = 0; i < k; ++i) {
        const float4* p4 = (const float4*)(Pb + (size_t)(b * CPB + base_c + i) * 4096);
        #pragma unroll
        for (int j = 0; j < 4; ++j) {
            float4 v = p4[tid + j * 256];
            acc[j].x += v.x; acc[j].y += v.y; acc[j].z += v.z; acc[j].w += v.w;
        }
    }
    float4* o4 = (float4*)out;
    const size_t obase = ((size_t)b * T + (size_t)tt * 64) * 16;   // float4 units
    #pragma unroll
    for (int j = 0; j < 4; ++j) {
        int idx = tid + j * 256;               // float4 index within 64x64 tile
        float inv = lnS[idx >> 4];             // 16 float4 per row
        float4 v = acc[j];
        v.x *= inv; v.y *= inv; v.z *= inv; v.w *= inv;
        o4[obase + idx] = v;
    }
}

// ---------------------------------------------------------------------------
extern "C" void kernel_launch(void* const* d_in, const int* in_sizes, int n_in,
                              void* d_out, int out_size, void* d_ws, size_t ws_size,
                              hipStream_t stream) {
    const float* x  = (const float*)d_in[0];
    const float* Wk = (const float*)d_in[1];
    const float* bk = (const float*)d_in[2];
    const float* Wq = (const float*)d_in[3];
    const float* bq = (const float*)d_in[4];
    const float* Wv = (const float*)d_in[5];
    const float* bv = (const float*)d_in[6];
    float* out = (float*)d_out;

    char* ws = (char*)d_ws;
    size_t off = 0;
    short* Kf   = (short*)(ws + off); off += (size_t)M * H * 2;            // 2 MB
    short* Qf   = (short*)(ws + off); off += (size_t)M * H * 2;            // 2 MB
    short* Vf   = (short*)(ws + off); off += (size_t)M * H * 2;            // 2 MB
    short* Wt_g = (short*)(ws + off); off += (size_t)192 * C * 2;          // 384 KB
    float* Pb   = (float*)(ws + off); off += (size_t)BATCH * CPB * 4096 * 4; // 18.9 MB
    float* lnPb = (float*)(ws + off); off += (size_t)BATCH * CPB * 64 * 4;   // 295 KB
    // total ~25.6 MB

    wtrans_kernel<<<48, 256, 0, stream>>>(Wk, Wq, Wv, Wt_g);
    proj_kernel<<<M / 64, 512, 0, stream>>>(x, Wt_g, bk, bq, bv, Kf, Qf, Vf);
    attn_part_kernel<<<BATCH * CPB, 256, 0, stream>>>(Kf, Qf, Vf, Pb, lnPb);
    reduce_norm_kernel<<<BATCH * 64, 256, 0, stream>>>(Pb, lnPb, out);
}

// Round 10
// 149.286 us; speedup vs baseline: 1.2152x; 1.0004x over previous
//
#include <hip/hip_runtime.h>
#include <hip/hip_bf16.h>
#include <math.h>

// B=4, T=4096, C=1024, H=64 attention head, scores = K@Q^T, causal, softmax over s.
// R19 FAILED (NaN): stage[(mat&1 ? 4096 : mat<<11)] — 2<<11 = 4096, NOT 8192; V
// fragments clobbered Q's stage region and V's region was never staged -> garbage
// LDS streamed into Vf. R20 (this round): identical kernel, one-line fix:
// stage[mat * 4096 + o]. Mechanism unchanged:
// (a) proj epilogue: stage fragments in dead Ws[0] LDS -> 3 coalesced bf16x8
//     stores/thread (TA /8 vs 24 scattered b16 stores).
// (b) attn epilogue: merge sums into Ob ([64][68], 16B rows) -> 1024 coalesced
//     float4 slab stores (TA /4 vs 32 scattered dwords).
// Keep: setprio, raw v_exp, native cvt, fragment-native K/Q/V loads, 4 dispatches.

typedef __attribute__((ext_vector_type(8))) short bf16x8;
typedef __attribute__((ext_vector_type(4))) short bf16x4;
typedef __attribute__((ext_vector_type(4))) float f32x4;

#define MFMA16(a, b, c) __builtin_amdgcn_mfma_f32_16x16x32_bf16(a, b, c, 0, 0, 0)

__device__ __forceinline__ short f2bf(float f) {
    __hip_bfloat16 h = __float2bfloat16(f);    // RNE; lowers to v_cvt_pk_bf16_f32
    return *reinterpret_cast<short*>(&h);
}

#if __has_builtin(__builtin_amdgcn_exp2f)
__device__ __forceinline__ float fexp2(float x) { return __builtin_amdgcn_exp2f(x); }
#else
__device__ __forceinline__ float fexp2(float x) { return exp2f(x); }
#endif

static constexpr int T = 4096;
static constexpr int C = 1024;
static constexpr int H = 64;
static constexpr int BATCH = 4;
static constexpr int M = BATCH * T;
static constexpr int CPB = 288;            // chunks per batch at CH=8 s-tiles/chunk
static constexpr float LOG2E = 1.44269504088896340736f;
static constexpr float KSCALE = 0.03125f * LOG2E;  // C^-0.5 * log2(e), folded into K

// Fragment layout per 64x64 tile (4096 shorts): off = sub16*1024 + half*512 +
// lane*8 + j. K/Q: sub16=row/16, (half,q,j) from h: half=h>>5, q=(h&31)>>3, j=h&7,
// lane=q*16+(row&15). V: sub16=h/16, half=s>>5, q=(s&31)>>3, j=s&7, lane=q*16+(h&15).

// ---------------------------------------------------------------------------
// Kernel 1: W -> bf16 transposed [192][1024] (LDS transpose). 48 blocks.
// ---------------------------------------------------------------------------
__global__ __launch_bounds__(256) void wtrans_kernel(
    const float* __restrict__ Wk, const float* __restrict__ Wq,
    const float* __restrict__ Wv, short* __restrict__ Wt_g)
{
    const int blk = blockIdx.x;
    const int tid = threadIdx.x;
    __shared__ short Wl[64][72];
    const int mat = blk / 16, k0 = (blk % 16) * 64;
    const float* W = (mat == 0) ? Wk : (mat == 1) ? Wq : Wv;
    const int hr = (tid & 15) * 4, kr = tid >> 4;
    #pragma unroll
    for (int pass = 0; pass < 4; ++pass) {
        int k = kr + pass * 16;
        float4 v = *(const float4*)&W[(size_t)(k0 + k) * H + hr];
        Wl[hr + 0][k] = f2bf(v.x);
        Wl[hr + 1][k] = f2bf(v.y);
        Wl[hr + 2][k] = f2bf(v.z);
        Wl[hr + 3][k] = f2bf(v.w);
    }
    __syncthreads();
    const int h = tid >> 2, kk = (tid & 3) * 16;
    bf16x8 o0 = *(const bf16x8*)&Wl[h][kk];
    bf16x8 o1 = *(const bf16x8*)&Wl[h][kk + 8];
    *(bf16x8*)&Wt_g[(size_t)(mat * 64 + h) * C + k0 + kk] = o0;
    *(bf16x8*)&Wt_g[(size_t)(mat * 64 + h) * C + k0 + kk + 8] = o1;
}

// ---------------------------------------------------------------------------
// Kernel 2: fused projection (R9 core), double-buffered LDS, one barrier per
// K-step. BM=64, BK=64, 512 threads. K pre-scaled. Epilogue stages fragments
// in dead Ws[0] LDS, then coalesced 16B stores (TA-lean).
// ---------------------------------------------------------------------------
__global__ __launch_bounds__(512) void proj_kernel(
    const float* __restrict__ x, const short* __restrict__ Wt_g,
    const float* __restrict__ bk, const float* __restrict__ bq,
    const float* __restrict__ bv,
    short* __restrict__ Kf, short* __restrict__ Qf, short* __restrict__ Vf)
{
    __shared__ short As[2][64][72];
    __shared__ short Ws[2][192][72];
    const int tid = threadIdx.x;
    const int wv = tid >> 6, lane = tid & 63, quad = lane >> 4, l16 = lane & 15;
    const int grp = wv >> 2, w4 = wv & 3;
    const int m0 = blockIdx.x * 64;
    const int arow = tid >> 3, ac8 = (tid & 7) * 8;

    f32x4 acc[6];
    #pragma unroll
    for (int i = 0; i < 6; ++i)
        for (int j = 0; j < 4; ++j) acc[i][j] = 0.f;

    float4 xa0, xa1;
    bf16x8 wl[3];
    auto gload = [&](int k0) {
        xa0 = *(const float4*)&x[(size_t)(m0 + arow) * C + k0 + ac8];
        xa1 = *(const float4*)&x[(size_t)(m0 + arow) * C + k0 + ac8 + 4];
        #pragma unroll
        for (int i = 0; i < 3; ++i) {
            int idx = tid + i * 512;
            wl[i] = *(const bf16x8*)&Wt_g[(size_t)(idx >> 3) * C + k0 + (idx & 7) * 8];
        }
    };
    auto lwrite = [&](int p) {
        bf16x8 av;
        av[0] = f2bf(xa0.x); av[1] = f2bf(xa0.y); av[2] = f2bf(xa0.z); av[3] = f2bf(xa0.w);
        av[4] = f2bf(xa1.x); av[5] = f2bf(xa1.y); av[6] = f2bf(xa1.z); av[7] = f2bf(xa1.w);
        *(bf16x8*)&As[p][arow][ac8] = av;
        #pragma unroll
        for (int i = 0; i < 3; ++i) {
            int idx = tid + i * 512;
            *(bf16x8*)&Ws[p][idx >> 3][(idx & 7) * 8] = wl[i];
        }
    };

    gload(0);
    lwrite(0);
    __syncthreads();
    for (int it = 0; it < 16; ++it) {
        const int p = it & 1;
        if (it < 15) gload((it + 1) * 64);
        bf16x8 a0 = *(const bf16x8*)&As[p][w4 * 16 + l16][quad * 8];
        bf16x8 a1 = *(const bf16x8*)&As[p][w4 * 16 + l16][32 + quad * 8];
        #pragma unroll
        for (int tn = 0; tn < 6; ++tn) {
            bf16x8 b0 = *(const bf16x8*)&Ws[p][grp * 96 + tn * 16 + l16][quad * 8];
            bf16x8 b1 = *(const bf16x8*)&Ws[p][grp * 96 + tn * 16 + l16][32 + quad * 8];
            acc[tn] = MFMA16(a0, b0, acc[tn]);
            acc[tn] = MFMA16(a1, b1, acc[tn]);
        }
        if (it < 15) {
            lwrite((it + 1) & 1);
            __syncthreads();
        }
    }
    // ---- epilogue: stage fragment-order into dead Ws[0] (13824 >= 12288 shorts);
    // Ws[0]'s last readers (it=14) are behind that iteration's ending barrier.
    short* stage = &Ws[0][0][0];
    #pragma unroll
    for (int tn = 0; tn < 6; ++tn) {
        int gc = grp * 96 + tn * 16 + l16;
        int mat = gc >> 6, h = gc & 63;
        const float* bias = (mat == 0) ? bk : (mat == 1) ? bq : bv;
        float bb = bias[h];
        float sc = (mat == 0) ? KSCALE : 1.f;
        #pragma unroll
        for (int r = 0; r < 4; ++r) {
            int s = w4 * 16 + quad * 4 + r;          // row within 64-tile
            short val = f2bf((acc[tn][r] + bb) * sc);
            int o;
            if (mat == 2) {
                o = (h >> 4) * 1024 + (s >> 5) * 512
                    + ((((s & 31) >> 3) * 16) + (h & 15)) * 8 + (s & 7);
            } else {
                o = (s >> 4) * 1024 + (h >> 5) * 512
                    + ((((h & 31) >> 3) * 16) + (s & 15)) * 8 + (h & 7);
            }
            stage[mat * 4096 + o] = val;             // R19 bug was mat<<11 here
        }
    }
    __syncthreads();
    const size_t tbase = (size_t)blockIdx.x * 4096;
    #pragma unroll
    for (int i = 0; i < 3; ++i) {
        int idx = tid + i * 512;                     // 0..1535 vec-index
        int mat = idx >> 9, voff = (idx & 511) * 8;
        short* dst = (mat == 0) ? Kf : (mat == 1) ? Qf : Vf;
        *(bf16x8*)&dst[tbase + voff] = *(const bf16x8*)&stage[mat * 4096 + voff];
    }
}

// ---------------------------------------------------------------------------
// chunk mapping (CH=8): t-tile tt has k = tt/8+1 chunks; group k (tiles
// 8(k-1)..8k-1) starts at c = 4k(k-1) and holds 8k chunks. Chunks of a tile
// are CONTIGUOUS: base_c(tt) = 4k(k-1) + (tt-8(k-1))*k.
// ---------------------------------------------------------------------------
__device__ __forceinline__ void chunk_map8(int c, int& tt, int& chunk) {
    int k = 1;
    while (c >= 4 * k * (k + 1)) ++k;          // k in [1,8]
    int off = c - 4 * k * (k - 1);
    int q = off / k;
    tt = 8 * (k - 1) + q;
    chunk = off - q * k;
}

// ---------------------------------------------------------------------------
// Kernel 3: flash attention partial. Fragment-native K/Q/V loads (1KB bursts).
// setprio around MFMA clusters. 4 waves/block; wave = (sh, sp). Epilogue:
// merge in Ob then cooperative coalesced float4 slab store. NO ATOMICS/FENCES.
// ---------------------------------------------------------------------------
__global__ __launch_bounds__(256) void attn_part_kernel(
    const short* __restrict__ Kf, const short* __restrict__ Qf,
    const short* __restrict__ Vf, float* __restrict__ Pb,
    float* __restrict__ lnPb)
{
    __shared__ short Pl[4][2][16][76];         // [wave][strip][t16][s]
    __shared__ float Ob[64][68];               // merge buffer (16B-aligned rows)
    __shared__ float lnb[64];
    const int tid = threadIdx.x;
    const int wv = tid >> 6, lane = tid & 63;
    const int quad = lane >> 4, l16 = lane & 15;
    const int sp = wv & 1, sh = wv >> 1;       // strip-pair, s-half
    const int g = blockIdx.x;                  // 0..1151
    const int b = g & 3;                       // batch pinned per XCD
    const int c = CPB - 1 - (g >> 2);          // 0..287, heavy-first
    int tt, chunk;
    chunk_map8(c, tt, chunk);
    const int sA = sp * 2, sB = sp * 2 + 1;    // this wave's two strips (t-sub16s)
    const int st0 = chunk * 8;
    const int st1 = min(st0 + 8, tt + 1);

    // K fragments: contiguous 1KB bursts at lane*8 shorts
    const short* kt = Kf + (size_t)(b * 64 + tt) * 4096 + lane * 8;
    bf16x8 kf0a = *(const bf16x8*)(kt + sA * 1024);
    bf16x8 kf1a = *(const bf16x8*)(kt + sA * 1024 + 512);
    bf16x8 kf0b = *(const bf16x8*)(kt + sB * 1024);
    bf16x8 kf1b = *(const bf16x8*)(kt + sB * 1024 + 512);

    bf16x8 ones;
    #pragma unroll
    for (int j = 0; j < 8; ++j) ones[j] = (short)0x3F80;   // bf16 1.0

    f32x4 oA[4], oB[4], lnA, lnB;
    #pragma unroll
    for (int i = 0; i < 4; ++i)
        for (int j = 0; j < 4; ++j) { oA[i][j] = 0.f; oB[i][j] = 0.f; }
    #pragma unroll
    for (int j = 0; j < 4; ++j) { lnA[j] = 0.f; lnB[j] = 0.f; }

    // this wave's s-tiles: st0+sh, st0+sh+2, ... (interleaved for balance)
    const int myb = st0 + sh;
    const short* qp = Qf + (size_t)(b * 64 + myb) * 4096 + lane * 8;
    const short* vp = Vf + (size_t)(b * 64 + myb) * 4096 + lane * 8;

    bf16x8 qc0[4], qc1[4];
    if (myb < st1) {
        #pragma unroll
        for (int tn = 0; tn < 4; ++tn) {
            qc0[tn] = *(const bf16x8*)(qp + tn * 1024);
            qc1[tn] = *(const bf16x8*)(qp + tn * 1024 + 512);
        }
    }

    for (int st = myb; st < st1; st += 2) {
        bf16x8 vb0[4], vb1[4];
        #pragma unroll
        for (int hn = 0; hn < 4; ++hn) {
            vb0[hn] = *(const bf16x8*)(vp + hn * 1024);
            vb1[hn] = *(const bf16x8*)(vp + hn * 1024 + 512);
        }
        // S^T for both strips: D[row=quad*4+r -> s][col=l16 -> t]
        f32x4 sAc[4], sBc[4];
        __builtin_amdgcn_s_setprio(1);
        #pragma unroll
        for (int tn = 0; tn < 4; ++tn) {
            #pragma unroll
            for (int j = 0; j < 4; ++j) { sAc[tn][j] = 0.f; sBc[tn][j] = 0.f; }
            sAc[tn] = MFMA16(qc0[tn], kf0a, sAc[tn]);
            sAc[tn] = MFMA16(qc1[tn], kf1a, sAc[tn]);
            sBc[tn] = MFMA16(qc0[tn], kf0b, sBc[tn]);
            sBc[tn] = MFMA16(qc1[tn], kf1b, sBc[tn]);
        }
        __builtin_amdgcn_s_setprio(0);
        // Q regs now dead -> load tile st+2's Q (covered by exp+LDS+PV below)
        const size_t qoff = (st + 2 < st1) ? 8192 : 0;
        #pragma unroll
        for (int tn = 0; tn < 4; ++tn) {
            qc0[tn] = *(const bf16x8*)(qp + qoff + tn * 1024);
            qc1[tn] = *(const bf16x8*)(qp + qoff + tn * 1024 + 512);
        }
        // p = exp2(s); mask only on the diagonal tile
        const bool diag = (st == tt);
        #pragma unroll
        for (int tn = 0; tn < 4; ++tn) {
            bf16x4 pa, pb;
            #pragma unroll
            for (int r = 0; r < 4; ++r) {
                float va = sAc[tn][r], vb = sBc[tn][r];
                if (diag) {
                    int scol = tn * 16 + quad * 4 + r;
                    if (scol > sA * 16 + l16) va = -INFINITY;
                    if (scol > sB * 16 + l16) vb = -INFINITY;
                }
                pa[r] = f2bf(fexp2(va));
                pb[r] = f2bf(fexp2(vb));
            }
            *(bf16x4*)&Pl[wv][0][l16][tn * 16 + quad * 4] = pa;
            *(bf16x4*)&Pl[wv][1][l16][tn * 16 + quad * 4] = pb;
        }
        // PV for both strips: A[m=t=l16][k=s] contiguous read-back
        bf16x8 aA0 = *(const bf16x8*)&Pl[wv][0][l16][quad * 8];
        bf16x8 aA1 = *(const bf16x8*)&Pl[wv][0][l16][32 + quad * 8];
        bf16x8 aB0 = *(const bf16x8*)&Pl[wv][1][l16][quad * 8];
        bf16x8 aB1 = *(const bf16x8*)&Pl[wv][1][l16][32 + quad * 8];
        __builtin_amdgcn_s_setprio(1);
        #pragma unroll
        for (int hn = 0; hn < 4; ++hn) {
            oA[hn] = MFMA16(aA0, vb0[hn], oA[hn]);
            oA[hn] = MFMA16(aA1, vb1[hn], oA[hn]);
            oB[hn] = MFMA16(aB0, vb0[hn], oB[hn]);
            oB[hn] = MFMA16(aB1, vb1[hn], oB[hn]);
        }
        lnA = MFMA16(aA0, ones, lnA);
        lnA = MFMA16(aA1, ones, lnA);
        lnB = MFMA16(aB0, ones, lnB);
        lnB = MFMA16(aB1, ones, lnB);
        __builtin_amdgcn_s_setprio(0);
        qp += 8192;
        vp += 8192;
    }

    // s-half merge: sh==1 stages partials; sh==0 adds, writes sums back to Ob;
    // then ALL waves store the 64x64 slab as coalesced float4.
    const int rbase = sp * 32;
    if (sh == 1) {
        #pragma unroll
        for (int hn = 0; hn < 4; ++hn)
            #pragma unroll
            for (int r = 0; r < 4; ++r) {
                Ob[rbase + quad * 4 + r][hn * 16 + l16] = oA[hn][r];
                Ob[rbase + 16 + quad * 4 + r][hn * 16 + l16] = oB[hn][r];
            }
        if (l16 == 0) {
            #pragma unroll
            for (int r = 0; r < 4; ++r) {
                lnb[rbase + quad * 4 + r] = lnA[r];
                lnb[rbase + 16 + quad * 4 + r] = lnB[r];
            }
        }
    }
    __syncthreads();
    if (sh == 0) {
        #pragma unroll
        for (int hn = 0; hn < 4; ++hn)
            #pragma unroll
            for (int r = 0; r < 4; ++r) {
                int ra = rbase + quad * 4 + r;
                int rb = ra + 16;
                Ob[ra][hn * 16 + l16] += oA[hn][r];
                Ob[rb][hn * 16 + l16] += oB[hn][r];
            }
        if (l16 == 0) {
            float* lc = lnPb + (size_t)(b * CPB + c) * 64;
            #pragma unroll
            for (int r = 0; r < 4; ++r) {
                lc[rbase + quad * 4 + r] = lnA[r] + lnb[rbase + quad * 4 + r];
                lc[rbase + 16 + quad * 4 + r] = lnB[r] + lnb[rbase + 16 + quad * 4 + r];
            }
        }
    }
    __syncthreads();
    float4* Pc4 = (float4*)(Pb + (size_t)(b * CPB + c) * 4096);
    #pragma unroll
    for (int i = 0; i < 4; ++i) {
        int idx = tid + i * 256;                   // 0..1023 float4 index
        int row = idx >> 4, c4 = (idx & 15) * 4;
        Pc4[idx] = *(const float4*)&Ob[row][c4];
    }
}

// ---------------------------------------------------------------------------
// Kernel 4: reduce <=8 contiguous chunk partials per t-tile, normalize, write out.
// Grid: BATCH*64 blocks of 256 threads.
// ---------------------------------------------------------------------------
__global__ __launch_bounds__(256) void reduce_norm_kernel(
    const float* __restrict__ Pb, const float* __restrict__ lnPb,
    float* __restrict__ out)
{
    const int blk = blockIdx.x;                // b*64 + tt
    const int b = blk >> 6, tt = blk & 63;
    const int k = tt / 8 + 1;                  // number of chunk partials
    const int base_c = 4 * k * (k - 1) + (tt - 8 * (k - 1)) * k;
    const int tid = threadIdx.x;
    __shared__ float lnS[64];
    if (tid < 64) {
        float s = 0.f;
        for (int i = 0; i < k; ++i)
            s += lnPb[(size_t)(b * CPB + base_c + i) * 64 + tid];
        lnS[tid] = 1.f / s;
    }
    __syncthreads();
    float4 acc[4];
    #pragma unroll
    for (int j = 0; j < 4; ++j) acc[j] = {0.f, 0.f, 0.f, 0.f};
    for (int i = 0; i < k; ++i) {
        const float4* p4 = (const float4*)(Pb + (size_t)(b * CPB + base_c + i) * 4096);
        #pragma unroll
        for (int j = 0; j < 4; ++j) {
            float4 v = p4[tid + j * 256];
            acc[j].x += v.x; acc[j].y += v.y; acc[j].z += v.z; acc[j].w += v.w;
        }
    }
    float4* o4 = (float4*)out;
    const size_t obase = ((size_t)b * T + (size_t)tt * 64) * 16;   // float4 units
    #pragma unroll
    for (int j = 0; j < 4; ++j) {
        int idx = tid + j * 256;               // float4 index within 64x64 tile
        float inv = lnS[idx >> 4];             // 16 float4 per row
        float4 v = acc[j];
        v.x *= inv; v.y *= inv; v.z *= inv; v.w *= inv;
        o4[obase + idx] = v;
    }
}

// ---------------------------------------------------------------------------
extern "C" void kernel_launch(void* const* d_in, const int* in_sizes, int n_in,
                              void* d_out, int out_size, void* d_ws, size_t ws_size,
                              hipStream_t stream) {
    const float* x  = (const float*)d_in[0];
    const float* Wk = (const float*)d_in[1];
    const float* bk = (const float*)d_in[2];
    const float* Wq = (const float*)d_in[3];
    const float* bq = (const float*)d_in[4];
    const float* Wv = (const float*)d_in[5];
    const float* bv = (const float*)d_in[6];
    float* out = (float*)d_out;

    char* ws = (char*)d_ws;
    size_t off = 0;
    short* Kf   = (short*)(ws + off); off += (size_t)M * H * 2;            // 2 MB
    short* Qf   = (short*)(ws + off); off += (size_t)M * H * 2;            // 2 MB
    short* Vf   = (short*)(ws + off); off += (size_t)M * H * 2;            // 2 MB
    short* Wt_g = (short*)(ws + off); off += (size_t)192 * C * 2;          // 384 KB
    float* Pb   = (float*)(ws + off); off += (size_t)BATCH * CPB * 4096 * 4; // 18.9 MB
    float* lnPb = (float*)(ws + off); off += (size_t)BATCH * CPB * 64 * 4;   // 295 KB
    // total ~25.6 MB

    wtrans_kernel<<<48, 256, 0, stream>>>(Wk, Wq, Wv, Wt_g);
    proj_kernel<<<M / 64, 512, 0, stream>>>(x, Wt_g, bk, bq, bv, Kf, Qf, Vf);
    attn_part_kernel<<<BATCH * CPB, 256, 0, stream>>>(Kf, Qf, Vf, Pb, lnPb);
    reduce_norm_kernel<<<BATCH * 64, 256, 0, stream>>>(Pb, lnPb, out);
}

// Round 11
// 148.745 us; speedup vs baseline: 1.2196x; 1.0036x over previous
//
#include <hip/hip_runtime.h>
#include <hip/hip_bf16.h>
#include <math.h>

// B=4, T=4096, C=1024, H=64 attention head, scores = K@Q^T, causal, softmax over s.
// R20: epilogue coalescing neutral (149.3 flat) — post-R18, epilogue TA is off the
// critical path. R21 (this round): SOFTWARE-PIPELINE the attn inner loop (T15
// minimal form). S(st) is computed in the PREVIOUS iteration; iteration st does:
// V(st) load -> Q(st+2) load early -> exp/pack(st) [consumes prev S, covers Q] ->
// P read-back -> S-MFMA(st+2) [independent, hides LDS round-trip] -> PV(st).
// sAc/sBc reused (exp consumes before rewrite). Floors: MFMA ~5us, L2-feed ~8us,
// current attn ~27us -> chain is the gap. Keep: fragment-native K/Q/V, setprio,
// raw v_exp, native cvt, coalesced epilogues, 4 dispatches.

typedef __attribute__((ext_vector_type(8))) short bf16x8;
typedef __attribute__((ext_vector_type(4))) short bf16x4;
typedef __attribute__((ext_vector_type(4))) float f32x4;

#define MFMA16(a, b, c) __builtin_amdgcn_mfma_f32_16x16x32_bf16(a, b, c, 0, 0, 0)

__device__ __forceinline__ short f2bf(float f) {
    __hip_bfloat16 h = __float2bfloat16(f);    // RNE; lowers to v_cvt_pk_bf16_f32
    return *reinterpret_cast<short*>(&h);
}

#if __has_builtin(__builtin_amdgcn_exp2f)
__device__ __forceinline__ float fexp2(float x) { return __builtin_amdgcn_exp2f(x); }
#else
__device__ __forceinline__ float fexp2(float x) { return exp2f(x); }
#endif

static constexpr int T = 4096;
static constexpr int C = 1024;
static constexpr int H = 64;
static constexpr int BATCH = 4;
static constexpr int M = BATCH * T;
static constexpr int CPB = 288;            // chunks per batch at CH=8 s-tiles/chunk
static constexpr float LOG2E = 1.44269504088896340736f;
static constexpr float KSCALE = 0.03125f * LOG2E;  // C^-0.5 * log2(e), folded into K

// Fragment layout per 64x64 tile (4096 shorts): off = sub16*1024 + half*512 +
// lane*8 + j. K/Q: sub16=row/16, (half,q,j) from h: half=h>>5, q=(h&31)>>3, j=h&7,
// lane=q*16+(row&15). V: sub16=h/16, half=s>>5, q=(s&31)>>3, j=s&7, lane=q*16+(h&15).

// ---------------------------------------------------------------------------
// Kernel 1: W -> bf16 transposed [192][1024] (LDS transpose). 48 blocks.
// ---------------------------------------------------------------------------
__global__ __launch_bounds__(256) void wtrans_kernel(
    const float* __restrict__ Wk, const float* __restrict__ Wq,
    const float* __restrict__ Wv, short* __restrict__ Wt_g)
{
    const int blk = blockIdx.x;
    const int tid = threadIdx.x;
    __shared__ short Wl[64][72];
    const int mat = blk / 16, k0 = (blk % 16) * 64;
    const float* W = (mat == 0) ? Wk : (mat == 1) ? Wq : Wv;
    const int hr = (tid & 15) * 4, kr = tid >> 4;
    #pragma unroll
    for (int pass = 0; pass < 4; ++pass) {
        int k = kr + pass * 16;
        float4 v = *(const float4*)&W[(size_t)(k0 + k) * H + hr];
        Wl[hr + 0][k] = f2bf(v.x);
        Wl[hr + 1][k] = f2bf(v.y);
        Wl[hr + 2][k] = f2bf(v.z);
        Wl[hr + 3][k] = f2bf(v.w);
    }
    __syncthreads();
    const int h = tid >> 2, kk = (tid & 3) * 16;
    bf16x8 o0 = *(const bf16x8*)&Wl[h][kk];
    bf16x8 o1 = *(const bf16x8*)&Wl[h][kk + 8];
    *(bf16x8*)&Wt_g[(size_t)(mat * 64 + h) * C + k0 + kk] = o0;
    *(bf16x8*)&Wt_g[(size_t)(mat * 64 + h) * C + k0 + kk + 8] = o1;
}

// ---------------------------------------------------------------------------
// Kernel 2: fused projection (R9 core), double-buffered LDS, one barrier per
// K-step. BM=64, BK=64, 512 threads. K pre-scaled. Epilogue stages fragments
// in dead Ws[0] LDS, then coalesced 16B stores.
// ---------------------------------------------------------------------------
__global__ __launch_bounds__(512) void proj_kernel(
    const float* __restrict__ x, const short* __restrict__ Wt_g,
    const float* __restrict__ bk, const float* __restrict__ bq,
    const float* __restrict__ bv,
    short* __restrict__ Kf, short* __restrict__ Qf, short* __restrict__ Vf)
{
    __shared__ short As[2][64][72];
    __shared__ short Ws[2][192][72];
    const int tid = threadIdx.x;
    const int wv = tid >> 6, lane = tid & 63, quad = lane >> 4, l16 = lane & 15;
    const int grp = wv >> 2, w4 = wv & 3;
    const int m0 = blockIdx.x * 64;
    const int arow = tid >> 3, ac8 = (tid & 7) * 8;

    f32x4 acc[6];
    #pragma unroll
    for (int i = 0; i < 6; ++i)
        for (int j = 0; j < 4; ++j) acc[i][j] = 0.f;

    float4 xa0, xa1;
    bf16x8 wl[3];
    auto gload = [&](int k0) {
        xa0 = *(const float4*)&x[(size_t)(m0 + arow) * C + k0 + ac8];
        xa1 = *(const float4*)&x[(size_t)(m0 + arow) * C + k0 + ac8 + 4];
        #pragma unroll
        for (int i = 0; i < 3; ++i) {
            int idx = tid + i * 512;
            wl[i] = *(const bf16x8*)&Wt_g[(size_t)(idx >> 3) * C + k0 + (idx & 7) * 8];
        }
    };
    auto lwrite = [&](int p) {
        bf16x8 av;
        av[0] = f2bf(xa0.x); av[1] = f2bf(xa0.y); av[2] = f2bf(xa0.z); av[3] = f2bf(xa0.w);
        av[4] = f2bf(xa1.x); av[5] = f2bf(xa1.y); av[6] = f2bf(xa1.z); av[7] = f2bf(xa1.w);
        *(bf16x8*)&As[p][arow][ac8] = av;
        #pragma unroll
        for (int i = 0; i < 3; ++i) {
            int idx = tid + i * 512;
            *(bf16x8*)&Ws[p][idx >> 3][(idx & 7) * 8] = wl[i];
        }
    };

    gload(0);
    lwrite(0);
    __syncthreads();
    for (int it = 0; it < 16; ++it) {
        const int p = it & 1;
        if (it < 15) gload((it + 1) * 64);
        bf16x8 a0 = *(const bf16x8*)&As[p][w4 * 16 + l16][quad * 8];
        bf16x8 a1 = *(const bf16x8*)&As[p][w4 * 16 + l16][32 + quad * 8];
        #pragma unroll
        for (int tn = 0; tn < 6; ++tn) {
            bf16x8 b0 = *(const bf16x8*)&Ws[p][grp * 96 + tn * 16 + l16][quad * 8];
            bf16x8 b1 = *(const bf16x8*)&Ws[p][grp * 96 + tn * 16 + l16][32 + quad * 8];
            acc[tn] = MFMA16(a0, b0, acc[tn]);
            acc[tn] = MFMA16(a1, b1, acc[tn]);
        }
        if (it < 15) {
            lwrite((it + 1) & 1);
            __syncthreads();
        }
    }
    // ---- epilogue: stage fragment-order into dead Ws[0], then coalesced copy.
    short* stage = &Ws[0][0][0];
    #pragma unroll
    for (int tn = 0; tn < 6; ++tn) {
        int gc = grp * 96 + tn * 16 + l16;
        int mat = gc >> 6, h = gc & 63;
        const float* bias = (mat == 0) ? bk : (mat == 1) ? bq : bv;
        float bb = bias[h];
        float sc = (mat == 0) ? KSCALE : 1.f;
        #pragma unroll
        for (int r = 0; r < 4; ++r) {
            int s = w4 * 16 + quad * 4 + r;          // row within 64-tile
            short val = f2bf((acc[tn][r] + bb) * sc);
            int o;
            if (mat == 2) {
                o = (h >> 4) * 1024 + (s >> 5) * 512
                    + ((((s & 31) >> 3) * 16) + (h & 15)) * 8 + (s & 7);
            } else {
                o = (s >> 4) * 1024 + (h >> 5) * 512
                    + ((((h & 31) >> 3) * 16) + (s & 15)) * 8 + (h & 7);
            }
            stage[mat * 4096 + o] = val;
        }
    }
    __syncthreads();
    const size_t tbase = (size_t)blockIdx.x * 4096;
    #pragma unroll
    for (int i = 0; i < 3; ++i) {
        int idx = tid + i * 512;                     // 0..1535 vec-index
        int mat = idx >> 9, voff = (idx & 511) * 8;
        short* dst = (mat == 0) ? Kf : (mat == 1) ? Qf : Vf;
        *(bf16x8*)&dst[tbase + voff] = *(const bf16x8*)&stage[mat * 4096 + voff];
    }
}

// ---------------------------------------------------------------------------
// chunk mapping (CH=8): t-tile tt has k = tt/8+1 chunks; group k (tiles
// 8(k-1)..8k-1) starts at c = 4k(k-1) and holds 8k chunks. Chunks of a tile
// are CONTIGUOUS: base_c(tt) = 4k(k-1) + (tt-8(k-1))*k.
// ---------------------------------------------------------------------------
__device__ __forceinline__ void chunk_map8(int c, int& tt, int& chunk) {
    int k = 1;
    while (c >= 4 * k * (k + 1)) ++k;          // k in [1,8]
    int off = c - 4 * k * (k - 1);
    int q = off / k;
    tt = 8 * (k - 1) + q;
    chunk = off - q * k;
}

// ---------------------------------------------------------------------------
// Kernel 3: flash attention partial, SOFTWARE-PIPELINED. S(st) computed in the
// previous iteration; iteration st: V load -> Q(st+2) load -> exp/pack(st) ->
// P read-back -> S-MFMA(st+2) (hides LDS round-trip) -> PV(st).
// Fragment-native K/Q/V loads. 4 waves/block; wave = (sh, sp). NO ATOMICS/FENCES.
// ---------------------------------------------------------------------------
__global__ __launch_bounds__(256) void attn_part_kernel(
    const short* __restrict__ Kf, const short* __restrict__ Qf,
    const short* __restrict__ Vf, float* __restrict__ Pb,
    float* __restrict__ lnPb)
{
    __shared__ short Pl[4][2][16][76];         // [wave][strip][t16][s]
    __shared__ float Ob[64][68];               // merge buffer (16B-aligned rows)
    __shared__ float lnb[64];
    const int tid = threadIdx.x;
    const int wv = tid >> 6, lane = tid & 63;
    const int quad = lane >> 4, l16 = lane & 15;
    const int sp = wv & 1, sh = wv >> 1;       // strip-pair, s-half
    const int g = blockIdx.x;                  // 0..1151
    const int b = g & 3;                       // batch pinned per XCD
    const int c = CPB - 1 - (g >> 2);          // 0..287, heavy-first
    int tt, chunk;
    chunk_map8(c, tt, chunk);
    const int sA = sp * 2, sB = sp * 2 + 1;    // this wave's two strips (t-sub16s)
    const int st0 = chunk * 8;
    const int st1 = min(st0 + 8, tt + 1);

    // K fragments: contiguous 1KB bursts at lane*8 shorts
    const short* kt = Kf + (size_t)(b * 64 + tt) * 4096 + lane * 8;
    bf16x8 kf0a = *(const bf16x8*)(kt + sA * 1024);
    bf16x8 kf1a = *(const bf16x8*)(kt + sA * 1024 + 512);
    bf16x8 kf0b = *(const bf16x8*)(kt + sB * 1024);
    bf16x8 kf1b = *(const bf16x8*)(kt + sB * 1024 + 512);

    bf16x8 ones;
    #pragma unroll
    for (int j = 0; j < 8; ++j) ones[j] = (short)0x3F80;   // bf16 1.0

    f32x4 oA[4], oB[4], lnA, lnB;
    #pragma unroll
    for (int i = 0; i < 4; ++i)
        for (int j = 0; j < 4; ++j) { oA[i][j] = 0.f; oB[i][j] = 0.f; }
    #pragma unroll
    for (int j = 0; j < 4; ++j) { lnA[j] = 0.f; lnB[j] = 0.f; }

    // this wave's s-tiles: st0+sh, st0+sh+2, ... (interleaved for balance)
    const int myb = st0 + sh;
    const short* qp = Qf + (size_t)(b * 64 + myb) * 4096 + lane * 8;
    const short* vp = Vf + (size_t)(b * 64 + myb) * 4096 + lane * 8;

    bf16x8 qc0[4], qc1[4];
    f32x4 sAc[4], sBc[4];
    // prologue: Q(myb) + S(myb)
    if (myb < st1) {
        #pragma unroll
        for (int tn = 0; tn < 4; ++tn) {
            qc0[tn] = *(const bf16x8*)(qp + tn * 1024);
            qc1[tn] = *(const bf16x8*)(qp + tn * 1024 + 512);
        }
        __builtin_amdgcn_s_setprio(1);
        #pragma unroll
        for (int tn = 0; tn < 4; ++tn) {
            #pragma unroll
            for (int j = 0; j < 4; ++j) { sAc[tn][j] = 0.f; sBc[tn][j] = 0.f; }
            sAc[tn] = MFMA16(qc0[tn], kf0a, sAc[tn]);
            sAc[tn] = MFMA16(qc1[tn], kf1a, sAc[tn]);
            sBc[tn] = MFMA16(qc0[tn], kf0b, sBc[tn]);
            sBc[tn] = MFMA16(qc1[tn], kf1b, sBc[tn]);
        }
        __builtin_amdgcn_s_setprio(0);
    }

    for (int st = myb; st < st1; st += 2) {
        // V(st) fragments (consumed by PV at the end)
        bf16x8 vb0[4], vb1[4];
        #pragma unroll
        for (int hn = 0; hn < 4; ++hn) {
            vb0[hn] = *(const bf16x8*)(vp + hn * 1024);
            vb1[hn] = *(const bf16x8*)(vp + hn * 1024 + 512);
        }
        // Q(st+2) load, issued early — covered by exp/pack below
        const size_t qoff = (st + 2 < st1) ? 8192 : 0;
        #pragma unroll
        for (int tn = 0; tn < 4; ++tn) {
            qc0[tn] = *(const bf16x8*)(qp + qoff + tn * 1024);
            qc1[tn] = *(const bf16x8*)(qp + qoff + tn * 1024 + 512);
        }
        // exp/pack(st) — consumes sAc/sBc (computed last iteration)
        const bool diag = (st == tt);
        #pragma unroll
        for (int tn = 0; tn < 4; ++tn) {
            bf16x4 pa, pb;
            #pragma unroll
            for (int r = 0; r < 4; ++r) {
                float va = sAc[tn][r], vb = sBc[tn][r];
                if (diag) {
                    int scol = tn * 16 + quad * 4 + r;
                    if (scol > sA * 16 + l16) va = -INFINITY;
                    if (scol > sB * 16 + l16) vb = -INFINITY;
                }
                pa[r] = f2bf(fexp2(va));
                pb[r] = f2bf(fexp2(vb));
            }
            *(bf16x4*)&Pl[wv][0][l16][tn * 16 + quad * 4] = pa;
            *(bf16x4*)&Pl[wv][1][l16][tn * 16 + quad * 4] = pb;
        }
        // P read-back (LDS); latency hidden by the S-MFMA cluster below
        bf16x8 aA0 = *(const bf16x8*)&Pl[wv][0][l16][quad * 8];
        bf16x8 aA1 = *(const bf16x8*)&Pl[wv][0][l16][32 + quad * 8];
        bf16x8 aB0 = *(const bf16x8*)&Pl[wv][1][l16][quad * 8];
        bf16x8 aB1 = *(const bf16x8*)&Pl[wv][1][l16][32 + quad * 8];
        // S-MFMA for st+2 (independent of P; sAc/sBc reused after exp)
        if (st + 2 < st1) {
            __builtin_amdgcn_s_setprio(1);
            #pragma unroll
            for (int tn = 0; tn < 4; ++tn) {
                #pragma unroll
                for (int j = 0; j < 4; ++j) { sAc[tn][j] = 0.f; sBc[tn][j] = 0.f; }
                sAc[tn] = MFMA16(qc0[tn], kf0a, sAc[tn]);
                sAc[tn] = MFMA16(qc1[tn], kf1a, sAc[tn]);
                sBc[tn] = MFMA16(qc0[tn], kf0b, sBc[tn]);
                sBc[tn] = MFMA16(qc1[tn], kf1b, sBc[tn]);
            }
            __builtin_amdgcn_s_setprio(0);
        }
        // PV(st) for both strips
        __builtin_amdgcn_s_setprio(1);
        #pragma unroll
        for (int hn = 0; hn < 4; ++hn) {
            oA[hn] = MFMA16(aA0, vb0[hn], oA[hn]);
            oA[hn] = MFMA16(aA1, vb1[hn], oA[hn]);
            oB[hn] = MFMA16(aB0, vb0[hn], oB[hn]);
            oB[hn] = MFMA16(aB1, vb1[hn], oB[hn]);
        }
        lnA = MFMA16(aA0, ones, lnA);
        lnA = MFMA16(aA1, ones, lnA);
        lnB = MFMA16(aB0, ones, lnB);
        lnB = MFMA16(aB1, ones, lnB);
        __builtin_amdgcn_s_setprio(0);
        qp += 8192;
        vp += 8192;
    }

    // s-half merge: sh==1 stages partials; sh==0 adds, writes sums back to Ob;
    // then ALL waves store the 64x64 slab as coalesced float4.
    const int rbase = sp * 32;
    if (sh == 1) {
        #pragma unroll
        for (int hn = 0; hn < 4; ++hn)
            #pragma unroll
            for (int r = 0; r < 4; ++r) {
                Ob[rbase + quad * 4 + r][hn * 16 + l16] = oA[hn][r];
                Ob[rbase + 16 + quad * 4 + r][hn * 16 + l16] = oB[hn][r];
            }
        if (l16 == 0) {
            #pragma unroll
            for (int r = 0; r < 4; ++r) {
                lnb[rbase + quad * 4 + r] = lnA[r];
                lnb[rbase + 16 + quad * 4 + r] = lnB[r];
            }
        }
    }
    __syncthreads();
    if (sh == 0) {
        #pragma unroll
        for (int hn = 0; hn < 4; ++hn)
            #pragma unroll
            for (int r = 0; r < 4; ++r) {
                int ra = rbase + quad * 4 + r;
                int rb = ra + 16;
                Ob[ra][hn * 16 + l16] += oA[hn][r];
                Ob[rb][hn * 16 + l16] += oB[hn][r];
            }
        if (l16 == 0) {
            float* lc = lnPb + (size_t)(b * CPB + c) * 64;
            #pragma unroll
            for (int r = 0; r < 4; ++r) {
                lc[rbase + quad * 4 + r] = lnA[r] + lnb[rbase + quad * 4 + r];
                lc[rbase + 16 + quad * 4 + r] = lnB[r] + lnb[rbase + 16 + quad * 4 + r];
            }
        }
    }
    __syncthreads();
    float4* Pc4 = (float4*)(Pb + (size_t)(b * CPB + c) * 4096);
    #pragma unroll
    for (int i = 0; i < 4; ++i) {
        int idx = tid + i * 256;                   // 0..1023 float4 index
        int row = idx >> 4, c4 = (idx & 15) * 4;
        Pc4[idx] = *(const float4*)&Ob[row][c4];
    }
}

// ---------------------------------------------------------------------------
// Kernel 4: reduce <=8 contiguous chunk partials per t-tile, normalize, write out.
// Grid: BATCH*64 blocks of 256 threads.
// ---------------------------------------------------------------------------
__global__ __launch_bounds__(256) void reduce_norm_kernel(
    const float* __restrict__ Pb, const float* __restrict__ lnPb,
    float* __restrict__ out)
{
    const int blk = blockIdx.x;                // b*64 + tt
    const int b = blk >> 6, tt = blk & 63;
    const int k = tt / 8 + 1;                  // number of chunk partials
    const int base_c = 4 * k * (k - 1) + (tt - 8 * (k - 1)) * k;
    const int tid = threadIdx.x;
    __shared__ float lnS[64];
    if (tid < 64) {
        float s = 0.f;
        for (int i = 0; i < k; ++i)
            s += lnPb[(size_t)(b * CPB + base_c + i) * 64 + tid];
        lnS[tid] = 1.f / s;
    }
    __syncthreads();
    float4 acc[4];
    #pragma unroll
    for (int j = 0; j < 4; ++j) acc[j] = {0.f, 0.f, 0.f, 0.f};
    for (int i = 0; i < k; ++i) {
        const float4* p4 = (const float4*)(Pb + (size_t)(b * CPB + base_c + i) * 4096);
        #pragma unroll
        for (int j = 0; j < 4; ++j) {
            float4 v = p4[tid + j * 256];
            acc[j].x += v.x; acc[j].y += v.y; acc[j].z += v.z; acc[j].w += v.w;
        }
    }
    float4* o4 = (float4*)out;
    const size_t obase = ((size_t)b * T + (size_t)tt * 64) * 16;   // float4 units
    #pragma unroll
    for (int j = 0; j < 4; ++j) {
        int idx = tid + j * 256;               // float4 index within 64x64 tile
        float inv = lnS[idx >> 4];             // 16 float4 per row
        float4 v = acc[j];
        v.x *= inv; v.y *= inv; v.z *= inv; v.w *= inv;
        o4[obase + idx] = v;
    }
}

// ---------------------------------------------------------------------------
extern "C" void kernel_launch(void* const* d_in, const int* in_sizes, int n_in,
                              void* d_out, int out_size, void* d_ws, size_t ws_size,
                              hipStream_t stream) {
    const float* x  = (const float*)d_in[0];
    const float* Wk = (const float*)d_in[1];
    const float* bk = (const float*)d_in[2];
    const float* Wq = (const float*)d_in[3];
    const float* bq = (const float*)d_in[4];
    const float* Wv = (const float*)d_in[5];
    const float* bv = (const float*)d_in[6];
    float* out = (float*)d_out;

    char* ws = (char*)d_ws;
    size_t off = 0;
    short* Kf   = (short*)(ws + off); off += (size_t)M * H * 2;            // 2 MB
    short* Qf   = (short*)(ws + off); off += (size_t)M * H * 2;            // 2 MB
    short* Vf   = (short*)(ws + off); off += (size_t)M * H * 2;            // 2 MB
    short* Wt_g = (short*)(ws + off); off += (size_t)192 * C * 2;          // 384 KB
    float* Pb   = (float*)(ws + off); off += (size_t)BATCH * CPB * 4096 * 4; // 18.9 MB
    float* lnPb = (float*)(ws + off); off += (size_t)BATCH * CPB * 64 * 4;   // 295 KB
    // total ~25.6 MB

    wtrans_kernel<<<48, 256, 0, stream>>>(Wk, Wq, Wv, Wt_g);
    proj_kernel<<<M / 64, 512, 0, stream>>>(x, Wt_g, bk, bq, bv, Kf, Qf, Vf);
    attn_part_kernel<<<BATCH * CPB, 256, 0, stream>>>(Kf, Qf, Vf, Pb, lnPb);
    reduce_norm_kernel<<<BATCH * 64, 256, 0, stream>>>(Pb, lnPb, out);
}

// Round 12
// 147.223 us; speedup vs baseline: 1.2322x; 1.0103x over previous
//
#include <hip/hip_runtime.h>
#include <hip/hip_bf16.h>
#include <math.h>

// B=4, T=4096, C=1024, H=64 attention head, scores = K@Q^T, causal, softmax over s.
// R21: S-pipeline neutral -> chain exonerated. Model: attn feed (~150MB Q/V/K
// re-reads, 96% cache-served per FETCH_SIZE) is coming from L3, not L2 — current
// mapping gives each XCD a 6MB working set (> 4MB L2). R22 (this round):
// XCD-LOCALITY REMAP. Each XCD owns fixed chunk s-ranges of one batch:
// chunk-offsets {0,1,6,7} (64+56+16+8=144 blocks) and {2,3,4,5} (48+40+32+24=144)
// -> 8 XCDs x exactly 144 blocks, Q/V working set 512KB/XCD (L2-resident).
// blockIdx%8->XCD heuristic; wrong mapping = perf-neutral only (bijective remap;
// slab index c = base_c(tt)+chi so reduce_norm is unchanged).
// Keep: fragment-native K/Q/V, S-pipeline, setprio, raw v_exp, native cvt.

typedef __attribute__((ext_vector_type(8))) short bf16x8;
typedef __attribute__((ext_vector_type(4))) short bf16x4;
typedef __attribute__((ext_vector_type(4))) float f32x4;

#define MFMA16(a, b, c) __builtin_amdgcn_mfma_f32_16x16x32_bf16(a, b, c, 0, 0, 0)

__device__ __forceinline__ short f2bf(float f) {
    __hip_bfloat16 h = __float2bfloat16(f);    // RNE; lowers to v_cvt_pk_bf16_f32
    return *reinterpret_cast<short*>(&h);
}

#if __has_builtin(__builtin_amdgcn_exp2f)
__device__ __forceinline__ float fexp2(float x) { return __builtin_amdgcn_exp2f(x); }
#else
__device__ __forceinline__ float fexp2(float x) { return exp2f(x); }
#endif

static constexpr int T = 4096;
static constexpr int C = 1024;
static constexpr int H = 64;
static constexpr int BATCH = 4;
static constexpr int M = BATCH * T;
static constexpr int CPB = 288;            // chunks per batch at CH=8 s-tiles/chunk
static constexpr float LOG2E = 1.44269504088896340736f;
static constexpr float KSCALE = 0.03125f * LOG2E;  // C^-0.5 * log2(e), folded into K

// Fragment layout per 64x64 tile (4096 shorts): off = sub16*1024 + half*512 +
// lane*8 + j. K/Q: sub16=row/16, (half,q,j) from h: half=h>>5, q=(h&31)>>3, j=h&7,
// lane=q*16+(row&15). V: sub16=h/16, half=s>>5, q=(s&31)>>3, j=s&7, lane=q*16+(h&15).

// ---------------------------------------------------------------------------
// Kernel 1: W -> bf16 transposed [192][1024] (LDS transpose). 48 blocks.
// ---------------------------------------------------------------------------
__global__ __launch_bounds__(256) void wtrans_kernel(
    const float* __restrict__ Wk, const float* __restrict__ Wq,
    const float* __restrict__ Wv, short* __restrict__ Wt_g)
{
    const int blk = blockIdx.x;
    const int tid = threadIdx.x;
    __shared__ short Wl[64][72];
    const int mat = blk / 16, k0 = (blk % 16) * 64;
    const float* W = (mat == 0) ? Wk : (mat == 1) ? Wq : Wv;
    const int hr = (tid & 15) * 4, kr = tid >> 4;
    #pragma unroll
    for (int pass = 0; pass < 4; ++pass) {
        int k = kr + pass * 16;
        float4 v = *(const float4*)&W[(size_t)(k0 + k) * H + hr];
        Wl[hr + 0][k] = f2bf(v.x);
        Wl[hr + 1][k] = f2bf(v.y);
        Wl[hr + 2][k] = f2bf(v.z);
        Wl[hr + 3][k] = f2bf(v.w);
    }
    __syncthreads();
    const int h = tid >> 2, kk = (tid & 3) * 16;
    bf16x8 o0 = *(const bf16x8*)&Wl[h][kk];
    bf16x8 o1 = *(const bf16x8*)&Wl[h][kk + 8];
    *(bf16x8*)&Wt_g[(size_t)(mat * 64 + h) * C + k0 + kk] = o0;
    *(bf16x8*)&Wt_g[(size_t)(mat * 64 + h) * C + k0 + kk + 8] = o1;
}

// ---------------------------------------------------------------------------
// Kernel 2: fused projection (R9 core), double-buffered LDS, one barrier per
// K-step. BM=64, BK=64, 512 threads. K pre-scaled. Epilogue stages fragments
// in dead Ws[0] LDS, then coalesced 16B stores.
// ---------------------------------------------------------------------------
__global__ __launch_bounds__(512) void proj_kernel(
    const float* __restrict__ x, const short* __restrict__ Wt_g,
    const float* __restrict__ bk, const float* __restrict__ bq,
    const float* __restrict__ bv,
    short* __restrict__ Kf, short* __restrict__ Qf, short* __restrict__ Vf)
{
    __shared__ short As[2][64][72];
    __shared__ short Ws[2][192][72];
    const int tid = threadIdx.x;
    const int wv = tid >> 6, lane = tid & 63, quad = lane >> 4, l16 = lane & 15;
    const int grp = wv >> 2, w4 = wv & 3;
    const int m0 = blockIdx.x * 64;
    const int arow = tid >> 3, ac8 = (tid & 7) * 8;

    f32x4 acc[6];
    #pragma unroll
    for (int i = 0; i < 6; ++i)
        for (int j = 0; j < 4; ++j) acc[i][j] = 0.f;

    float4 xa0, xa1;
    bf16x8 wl[3];
    auto gload = [&](int k0) {
        xa0 = *(const float4*)&x[(size_t)(m0 + arow) * C + k0 + ac8];
        xa1 = *(const float4*)&x[(size_t)(m0 + arow) * C + k0 + ac8 + 4];
        #pragma unroll
        for (int i = 0; i < 3; ++i) {
            int idx = tid + i * 512;
            wl[i] = *(const bf16x8*)&Wt_g[(size_t)(idx >> 3) * C + k0 + (idx & 7) * 8];
        }
    };
    auto lwrite = [&](int p) {
        bf16x8 av;
        av[0] = f2bf(xa0.x); av[1] = f2bf(xa0.y); av[2] = f2bf(xa0.z); av[3] = f2bf(xa0.w);
        av[4] = f2bf(xa1.x); av[5] = f2bf(xa1.y); av[6] = f2bf(xa1.z); av[7] = f2bf(xa1.w);
        *(bf16x8*)&As[p][arow][ac8] = av;
        #pragma unroll
        for (int i = 0; i < 3; ++i) {
            int idx = tid + i * 512;
            *(bf16x8*)&Ws[p][idx >> 3][(idx & 7) * 8] = wl[i];
        }
    };

    gload(0);
    lwrite(0);
    __syncthreads();
    for (int it = 0; it < 16; ++it) {
        const int p = it & 1;
        if (it < 15) gload((it + 1) * 64);
        bf16x8 a0 = *(const bf16x8*)&As[p][w4 * 16 + l16][quad * 8];
        bf16x8 a1 = *(const bf16x8*)&As[p][w4 * 16 + l16][32 + quad * 8];
        #pragma unroll
        for (int tn = 0; tn < 6; ++tn) {
            bf16x8 b0 = *(const bf16x8*)&Ws[p][grp * 96 + tn * 16 + l16][quad * 8];
            bf16x8 b1 = *(const bf16x8*)&Ws[p][grp * 96 + tn * 16 + l16][32 + quad * 8];
            acc[tn] = MFMA16(a0, b0, acc[tn]);
            acc[tn] = MFMA16(a1, b1, acc[tn]);
        }
        if (it < 15) {
            lwrite((it + 1) & 1);
            __syncthreads();
        }
    }
    // ---- epilogue: stage fragment-order into dead Ws[0], then coalesced copy.
    short* stage = &Ws[0][0][0];
    #pragma unroll
    for (int tn = 0; tn < 6; ++tn) {
        int gc = grp * 96 + tn * 16 + l16;
        int mat = gc >> 6, h = gc & 63;
        const float* bias = (mat == 0) ? bk : (mat == 1) ? bq : bv;
        float bb = bias[h];
        float sc = (mat == 0) ? KSCALE : 1.f;
        #pragma unroll
        for (int r = 0; r < 4; ++r) {
            int s = w4 * 16 + quad * 4 + r;          // row within 64-tile
            short val = f2bf((acc[tn][r] + bb) * sc);
            int o;
            if (mat == 2) {
                o = (h >> 4) * 1024 + (s >> 5) * 512
                    + ((((s & 31) >> 3) * 16) + (h & 15)) * 8 + (s & 7);
            } else {
                o = (s >> 4) * 1024 + (h >> 5) * 512
                    + ((((h & 31) >> 3) * 16) + (s & 15)) * 8 + (h & 7);
            }
            stage[mat * 4096 + o] = val;
        }
    }
    __syncthreads();
    const size_t tbase = (size_t)blockIdx.x * 4096;
    #pragma unroll
    for (int i = 0; i < 3; ++i) {
        int idx = tid + i * 512;                     // 0..1535 vec-index
        int mat = idx >> 9, voff = (idx & 511) * 8;
        short* dst = (mat == 0) ? Kf : (mat == 1) ? Qf : Vf;
        *(bf16x8*)&dst[tbase + voff] = *(const bf16x8*)&stage[mat * 4096 + voff];
    }
}

// ---------------------------------------------------------------------------
// Kernel 3: flash attention partial, software-pipelined, XCD-locality remapped.
// blockIdx%8 = target XCD x; b = x>>1 (one batch per XCD); x&1 selects the
// chunk-offset set {0,1,6,7} (counts 64,56,16,8) or {2,3,4,5} (48,40,32,24) —
// 144 blocks per XCD exactly; per-XCD Q/V working set 512KB (L2-resident).
// Fragment-native K/Q/V loads. 4 waves/block; wave = (sh, sp). NO ATOMICS/FENCES.
// ---------------------------------------------------------------------------
__global__ __launch_bounds__(256) void attn_part_kernel(
    const short* __restrict__ Kf, const short* __restrict__ Qf,
    const short* __restrict__ Vf, float* __restrict__ Pb,
    float* __restrict__ lnPb)
{
    __shared__ short Pl[4][2][16][76];         // [wave][strip][t16][s]
    __shared__ float Ob[64][68];               // merge buffer (16B-aligned rows)
    __shared__ float lnb[64];
    const int tid = threadIdx.x;
    const int wv = tid >> 6, lane = tid & 63;
    const int quad = lane >> 4, l16 = lane & 15;
    const int sp = wv & 1, sh = wv >> 1;       // strip-pair, s-half
    const int g = blockIdx.x;                  // 0..1151
    const int x = g & 7;                       // target XCD (blockIdx%8 heuristic)
    const int i = g >> 3;                      // 0..143 within XCD
    const int b = x >> 1;                      // one batch per XCD
    int tt, chi;
    if ((x & 1) == 0) {                        // chunk-offsets {0,1,6,7}
        if (i < 64)       { chi = 0; tt = i; }
        else if (i < 120) { chi = 1; tt = 8 + (i - 64); }
        else if (i < 136) { chi = 6; tt = 48 + (i - 120); }
        else              { chi = 7; tt = 56 + (i - 136); }
    } else {                                   // chunk-offsets {2,3,4,5}
        if (i < 48)       { chi = 2; tt = 16 + i; }
        else if (i < 88)  { chi = 3; tt = 24 + (i - 48); }
        else if (i < 120) { chi = 4; tt = 32 + (i - 88); }
        else              { chi = 5; tt = 40 + (i - 120); }
    }
    const int kch = tt / 8 + 1;                // chunks for this tile
    const int c = 4 * kch * (kch - 1) + (tt - 8 * (kch - 1)) * kch + chi;
    const int sA = sp * 2, sB = sp * 2 + 1;    // this wave's two strips (t-sub16s)
    const int st0 = chi * 8;
    const int st1 = min(st0 + 8, tt + 1);

    // K fragments: contiguous 1KB bursts at lane*8 shorts
    const short* kt = Kf + (size_t)(b * 64 + tt) * 4096 + lane * 8;
    bf16x8 kf0a = *(const bf16x8*)(kt + sA * 1024);
    bf16x8 kf1a = *(const bf16x8*)(kt + sA * 1024 + 512);
    bf16x8 kf0b = *(const bf16x8*)(kt + sB * 1024);
    bf16x8 kf1b = *(const bf16x8*)(kt + sB * 1024 + 512);

    bf16x8 ones;
    #pragma unroll
    for (int j = 0; j < 8; ++j) ones[j] = (short)0x3F80;   // bf16 1.0

    f32x4 oA[4], oB[4], lnA, lnB;
    #pragma unroll
    for (int i2 = 0; i2 < 4; ++i2)
        for (int j = 0; j < 4; ++j) { oA[i2][j] = 0.f; oB[i2][j] = 0.f; }
    #pragma unroll
    for (int j = 0; j < 4; ++j) { lnA[j] = 0.f; lnB[j] = 0.f; }

    // this wave's s-tiles: st0+sh, st0+sh+2, ... (interleaved for balance)
    const int myb = st0 + sh;
    const short* qp = Qf + (size_t)(b * 64 + myb) * 4096 + lane * 8;
    const short* vp = Vf + (size_t)(b * 64 + myb) * 4096 + lane * 8;

    bf16x8 qc0[4], qc1[4];
    f32x4 sAc[4], sBc[4];
    // prologue: Q(myb) + S(myb)
    if (myb < st1) {
        #pragma unroll
        for (int tn = 0; tn < 4; ++tn) {
            qc0[tn] = *(const bf16x8*)(qp + tn * 1024);
            qc1[tn] = *(const bf16x8*)(qp + tn * 1024 + 512);
        }
        __builtin_amdgcn_s_setprio(1);
        #pragma unroll
        for (int tn = 0; tn < 4; ++tn) {
            #pragma unroll
            for (int j = 0; j < 4; ++j) { sAc[tn][j] = 0.f; sBc[tn][j] = 0.f; }
            sAc[tn] = MFMA16(qc0[tn], kf0a, sAc[tn]);
            sAc[tn] = MFMA16(qc1[tn], kf1a, sAc[tn]);
            sBc[tn] = MFMA16(qc0[tn], kf0b, sBc[tn]);
            sBc[tn] = MFMA16(qc1[tn], kf1b, sBc[tn]);
        }
        __builtin_amdgcn_s_setprio(0);
    }

    for (int st = myb; st < st1; st += 2) {
        // V(st) fragments (consumed by PV at the end)
        bf16x8 vb0[4], vb1[4];
        #pragma unroll
        for (int hn = 0; hn < 4; ++hn) {
            vb0[hn] = *(const bf16x8*)(vp + hn * 1024);
            vb1[hn] = *(const bf16x8*)(vp + hn * 1024 + 512);
        }
        // Q(st+2) load, issued early — covered by exp/pack below
        const size_t qoff = (st + 2 < st1) ? 8192 : 0;
        #pragma unroll
        for (int tn = 0; tn < 4; ++tn) {
            qc0[tn] = *(const bf16x8*)(qp + qoff + tn * 1024);
            qc1[tn] = *(const bf16x8*)(qp + qoff + tn * 1024 + 512);
        }
        // exp/pack(st) — consumes sAc/sBc (computed last iteration)
        const bool diag = (st == tt);
        #pragma unroll
        for (int tn = 0; tn < 4; ++tn) {
            bf16x4 pa, pb;
            #pragma unroll
            for (int r = 0; r < 4; ++r) {
                float va = sAc[tn][r], vb = sBc[tn][r];
                if (diag) {
                    int scol = tn * 16 + quad * 4 + r;
                    if (scol > sA * 16 + l16) va = -INFINITY;
                    if (scol > sB * 16 + l16) vb = -INFINITY;
                }
                pa[r] = f2bf(fexp2(va));
                pb[r] = f2bf(fexp2(vb));
            }
            *(bf16x4*)&Pl[wv][0][l16][tn * 16 + quad * 4] = pa;
            *(bf16x4*)&Pl[wv][1][l16][tn * 16 + quad * 4] = pb;
        }
        // P read-back (LDS); latency hidden by the S-MFMA cluster below
        bf16x8 aA0 = *(const bf16x8*)&Pl[wv][0][l16][quad * 8];
        bf16x8 aA1 = *(const bf16x8*)&Pl[wv][0][l16][32 + quad * 8];
        bf16x8 aB0 = *(const bf16x8*)&Pl[wv][1][l16][quad * 8];
        bf16x8 aB1 = *(const bf16x8*)&Pl[wv][1][l16][32 + quad * 8];
        // S-MFMA for st+2 (independent of P; sAc/sBc reused after exp)
        if (st + 2 < st1) {
            __builtin_amdgcn_s_setprio(1);
            #pragma unroll
            for (int tn = 0; tn < 4; ++tn) {
                #pragma unroll
                for (int j = 0; j < 4; ++j) { sAc[tn][j] = 0.f; sBc[tn][j] = 0.f; }
                sAc[tn] = MFMA16(qc0[tn], kf0a, sAc[tn]);
                sAc[tn] = MFMA16(qc1[tn], kf1a, sAc[tn]);
                sBc[tn] = MFMA16(qc0[tn], kf0b, sBc[tn]);
                sBc[tn] = MFMA16(qc1[tn], kf1b, sBc[tn]);
            }
            __builtin_amdgcn_s_setprio(0);
        }
        // PV(st) for both strips
        __builtin_amdgcn_s_setprio(1);
        #pragma unroll
        for (int hn = 0; hn < 4; ++hn) {
            oA[hn] = MFMA16(aA0, vb0[hn], oA[hn]);
            oA[hn] = MFMA16(aA1, vb1[hn], oA[hn]);
            oB[hn] = MFMA16(aB0, vb0[hn], oB[hn]);
            oB[hn] = MFMA16(aB1, vb1[hn], oB[hn]);
        }
        lnA = MFMA16(aA0, ones, lnA);
        lnA = MFMA16(aA1, ones, lnA);
        lnB = MFMA16(aB0, ones, lnB);
        lnB = MFMA16(aB1, ones, lnB);
        __builtin_amdgcn_s_setprio(0);
        qp += 8192;
        vp += 8192;
    }

    // s-half merge: sh==1 stages partials; sh==0 adds, writes sums back to Ob;
    // then ALL waves store the 64x64 slab as coalesced float4.
    const int rbase = sp * 32;
    if (sh == 1) {
        #pragma unroll
        for (int hn = 0; hn < 4; ++hn)
            #pragma unroll
            for (int r = 0; r < 4; ++r) {
                Ob[rbase + quad * 4 + r][hn * 16 + l16] = oA[hn][r];
                Ob[rbase + 16 + quad * 4 + r][hn * 16 + l16] = oB[hn][r];
            }
        if (l16 == 0) {
            #pragma unroll
            for (int r = 0; r < 4; ++r) {
                lnb[rbase + quad * 4 + r] = lnA[r];
                lnb[rbase + 16 + quad * 4 + r] = lnB[r];
            }
        }
    }
    __syncthreads();
    if (sh == 0) {
        #pragma unroll
        for (int hn = 0; hn < 4; ++hn)
            #pragma unroll
            for (int r = 0; r < 4; ++r) {
                int ra = rbase + quad * 4 + r;
                int rb = ra + 16;
                Ob[ra][hn * 16 + l16] += oA[hn][r];
                Ob[rb][hn * 16 + l16] += oB[hn][r];
            }
        if (l16 == 0) {
            float* lc = lnPb + (size_t)(b * CPB + c) * 64;
            #pragma unroll
            for (int r = 0; r < 4; ++r) {
                lc[rbase + quad * 4 + r] = lnA[r] + lnb[rbase + quad * 4 + r];
                lc[rbase + 16 + quad * 4 + r] = lnB[r] + lnb[rbase + 16 + quad * 4 + r];
            }
        }
    }
    __syncthreads();
    float4* Pc4 = (float4*)(Pb + (size_t)(b * CPB + c) * 4096);
    #pragma unroll
    for (int i2 = 0; i2 < 4; ++i2) {
        int idx = tid + i2 * 256;                  // 0..1023 float4 index
        int row = idx >> 4, c4 = (idx & 15) * 4;
        Pc4[idx] = *(const float4*)&Ob[row][c4];
    }
}

// ---------------------------------------------------------------------------
// Kernel 4: reduce <=8 contiguous chunk partials per t-tile, normalize, write out.
// Grid: BATCH*64 blocks of 256 threads.
// ---------------------------------------------------------------------------
__global__ __launch_bounds__(256) void reduce_norm_kernel(
    const float* __restrict__ Pb, const float* __restrict__ lnPb,
    float* __restrict__ out)
{
    const int blk = blockIdx.x;                // b*64 + tt
    const int b = blk >> 6, tt = blk & 63;
    const int k = tt / 8 + 1;                  // number of chunk partials
    const int base_c = 4 * k * (k - 1) + (tt - 8 * (k - 1)) * k;
    const int tid = threadIdx.x;
    __shared__ float lnS[64];
    if (tid < 64) {
        float s = 0.f;
        for (int i = 0; i < k; ++i)
            s += lnPb[(size_t)(b * CPB + base_c + i) * 64 + tid];
        lnS[tid] = 1.f / s;
    }
    __syncthreads();
    float4 acc[4];
    #pragma unroll
    for (int j = 0; j < 4; ++j) acc[j] = {0.f, 0.f, 0.f, 0.f};
    for (int i = 0; i < k; ++i) {
        const float4* p4 = (const float4*)(Pb + (size_t)(b * CPB + base_c + i) * 4096);
        #pragma unroll
        for (int j = 0; j < 4; ++j) {
            float4 v = p4[tid + j * 256];
            acc[j].x += v.x; acc[j].y += v.y; acc[j].z += v.z; acc[j].w += v.w;
        }
    }
    float4* o4 = (float4*)out;
    const size_t obase = ((size_t)b * T + (size_t)tt * 64) * 16;   // float4 units
    #pragma unroll
    for (int j = 0; j < 4; ++j) {
        int idx = tid + j * 256;               // float4 index within 64x64 tile
        float inv = lnS[idx >> 4];             // 16 float4 per row
        float4 v = acc[j];
        v.x *= inv; v.y *= inv; v.z *= inv; v.w *= inv;
        o4[obase + idx] = v;
    }
}

// ---------------------------------------------------------------------------
extern "C" void kernel_launch(void* const* d_in, const int* in_sizes, int n_in,
                              void* d_out, int out_size, void* d_ws, size_t ws_size,
                              hipStream_t stream) {
    const float* x  = (const float*)d_in[0];
    const float* Wk = (const float*)d_in[1];
    const float* bk = (const float*)d_in[2];
    const float* Wq = (const float*)d_in[3];
    const float* bq = (const float*)d_in[4];
    const float* Wv = (const float*)d_in[5];
    const float* bv = (const float*)d_in[6];
    float* out = (float*)d_out;

    char* ws = (char*)d_ws;
    size_t off = 0;
    short* Kf   = (short*)(ws + off); off += (size_t)M * H * 2;            // 2 MB
    short* Qf   = (short*)(ws + off); off += (size_t)M * H * 2;            // 2 MB
    short* Vf   = (short*)(ws + off); off += (size_t)M * H * 2;            // 2 MB
    short* Wt_g = (short*)(ws + off); off += (size_t)192 * C * 2;          // 384 KB
    float* Pb   = (float*)(ws + off); off += (size_t)BATCH * CPB * 4096 * 4; // 18.9 MB
    float* lnPb = (float*)(ws + off); off += (size_t)BATCH * CPB * 64 * 4;   // 295 KB
    // total ~25.6 MB

    wtrans_kernel<<<48, 256, 0, stream>>>(Wk, Wq, Wv, Wt_g);
    proj_kernel<<<M / 64, 512, 0, stream>>>(x, Wt_g, bk, bq, bv, Kf, Qf, Vf);
    attn_part_kernel<<<BATCH * CPB, 256, 0, stream>>>(Kf, Qf, Vf, Pb, lnPb);
    reduce_norm_kernel<<<BATCH * 64, 256, 0, stream>>>(Pb, lnPb, out);
}

// Round 13
// 146.424 us; speedup vs baseline: 1.2389x; 1.0055x over previous
//
#include <hip/hip_runtime.h>
#include <hip/hip_bf16.h>
#include <math.h>

// B=4, T=4096, C=1024, H=64 attention head, scores = K@Q^T, causal, softmax over s.
// R22: XCD remap -1.5us (147.2). R23 (this round): PROJ CO-RESIDENCY. proj was
// 256 blocks = 1 block/CU; gload->lwrite HBM latency (~900cyc) has only ~200cyc
// MFMA cover and no second block to overlap -> ~700cyc exposed stall x16 iters.
// BM 64->32: 512 blocks x 256 thr (4 waves = 2 row-strips x 2 col-groups),
// LDS 64.5KB -> 2 blocks/CU co-resident, independent barriers overlap stalls.
// Epilogue: half-tile staging (K/Q contiguous at bh*2048; V four 512-runs at
// hn*1024+bh*512), bijectivity re-derived. attn/wtrans/reduce unchanged.
// Keep: fragment-native K/Q/V, S-pipeline, XCD remap, setprio, raw v_exp.

typedef __attribute__((ext_vector_type(8))) short bf16x8;
typedef __attribute__((ext_vector_type(4))) short bf16x4;
typedef __attribute__((ext_vector_type(4))) float f32x4;

#define MFMA16(a, b, c) __builtin_amdgcn_mfma_f32_16x16x32_bf16(a, b, c, 0, 0, 0)

__device__ __forceinline__ short f2bf(float f) {
    __hip_bfloat16 h = __float2bfloat16(f);    // RNE; lowers to v_cvt_pk_bf16_f32
    return *reinterpret_cast<short*>(&h);
}

#if __has_builtin(__builtin_amdgcn_exp2f)
__device__ __forceinline__ float fexp2(float x) { return __builtin_amdgcn_exp2f(x); }
#else
__device__ __forceinline__ float fexp2(float x) { return exp2f(x); }
#endif

static constexpr int T = 4096;
static constexpr int C = 1024;
static constexpr int H = 64;
static constexpr int BATCH = 4;
static constexpr int M = BATCH * T;
static constexpr int CPB = 288;            // chunks per batch at CH=8 s-tiles/chunk
static constexpr float LOG2E = 1.44269504088896340736f;
static constexpr float KSCALE = 0.03125f * LOG2E;  // C^-0.5 * log2(e), folded into K

// Fragment layout per 64x64 tile (4096 shorts): off = sub16*1024 + half*512 +
// lane*8 + j. K/Q: sub16=row/16, (half,q,j) from h: half=h>>5, q=(h&31)>>3, j=h&7,
// lane=q*16+(row&15). V: sub16=h/16, half=s>>5, q=(s&31)>>3, j=s&7, lane=q*16+(h&15).

// ---------------------------------------------------------------------------
// Kernel 1: W -> bf16 transposed [192][1024] (LDS transpose). 48 blocks.
// ---------------------------------------------------------------------------
__global__ __launch_bounds__(256) void wtrans_kernel(
    const float* __restrict__ Wk, const float* __restrict__ Wq,
    const float* __restrict__ Wv, short* __restrict__ Wt_g)
{
    const int blk = blockIdx.x;
    const int tid = threadIdx.x;
    __shared__ short Wl[64][72];
    const int mat = blk / 16, k0 = (blk % 16) * 64;
    const float* W = (mat == 0) ? Wk : (mat == 1) ? Wq : Wv;
    const int hr = (tid & 15) * 4, kr = tid >> 4;
    #pragma unroll
    for (int pass = 0; pass < 4; ++pass) {
        int k = kr + pass * 16;
        float4 v = *(const float4*)&W[(size_t)(k0 + k) * H + hr];
        Wl[hr + 0][k] = f2bf(v.x);
        Wl[hr + 1][k] = f2bf(v.y);
        Wl[hr + 2][k] = f2bf(v.z);
        Wl[hr + 3][k] = f2bf(v.w);
    }
    __syncthreads();
    const int h = tid >> 2, kk = (tid & 3) * 16;
    bf16x8 o0 = *(const bf16x8*)&Wl[h][kk];
    bf16x8 o1 = *(const bf16x8*)&Wl[h][kk + 8];
    *(bf16x8*)&Wt_g[(size_t)(mat * 64 + h) * C + k0 + kk] = o0;
    *(bf16x8*)&Wt_g[(size_t)(mat * 64 + h) * C + k0 + kk + 8] = o1;
}

// ---------------------------------------------------------------------------
// Kernel 2: fused projection, BM=32, 256 threads, 512 blocks (2 blocks/CU).
// 4 waves = 2 row-strips (w2) x 2 col-groups (grp, 96 cols each). Double-
// buffered LDS, one barrier per K-step. K pre-scaled. Epilogue stages the
// half-tile in dead Ws[0], then coalesced 16B stores.
// ---------------------------------------------------------------------------
__global__ __launch_bounds__(256) void proj_kernel(
    const float* __restrict__ x, const short* __restrict__ Wt_g,
    const float* __restrict__ bk, const float* __restrict__ bq,
    const float* __restrict__ bv,
    short* __restrict__ Kf, short* __restrict__ Qf, short* __restrict__ Vf)
{
    __shared__ short As[2][32][72];
    __shared__ short Ws[2][192][72];
    const int tid = threadIdx.x;
    const int wv = tid >> 6, lane = tid & 63, quad = lane >> 4, l16 = lane & 15;
    const int grp = wv >> 1, w2 = wv & 1;
    const int m0 = blockIdx.x * 32;
    const int arow = tid >> 3, ac8 = (tid & 7) * 8;   // 32 rows x 8 thr/row

    f32x4 acc[6];
    #pragma unroll
    for (int i = 0; i < 6; ++i)
        for (int j = 0; j < 4; ++j) acc[i][j] = 0.f;

    float4 xa0, xa1;
    bf16x8 wl[6];
    auto gload = [&](int k0) {
        xa0 = *(const float4*)&x[(size_t)(m0 + arow) * C + k0 + ac8];
        xa1 = *(const float4*)&x[(size_t)(m0 + arow) * C + k0 + ac8 + 4];
        #pragma unroll
        for (int i = 0; i < 6; ++i) {
            int idx = tid + i * 256;                 // 0..1535 = 192 rows x 8
            wl[i] = *(const bf16x8*)&Wt_g[(size_t)(idx >> 3) * C + k0 + (idx & 7) * 8];
        }
    };
    auto lwrite = [&](int p) {
        bf16x8 av;
        av[0] = f2bf(xa0.x); av[1] = f2bf(xa0.y); av[2] = f2bf(xa0.z); av[3] = f2bf(xa0.w);
        av[4] = f2bf(xa1.x); av[5] = f2bf(xa1.y); av[6] = f2bf(xa1.z); av[7] = f2bf(xa1.w);
        *(bf16x8*)&As[p][arow][ac8] = av;
        #pragma unroll
        for (int i = 0; i < 6; ++i) {
            int idx = tid + i * 256;
            *(bf16x8*)&Ws[p][idx >> 3][(idx & 7) * 8] = wl[i];
        }
    };

    gload(0);
    lwrite(0);
    __syncthreads();
    for (int it = 0; it < 16; ++it) {
        const int p = it & 1;
        if (it < 15) gload((it + 1) * 64);
        bf16x8 a0 = *(const bf16x8*)&As[p][w2 * 16 + l16][quad * 8];
        bf16x8 a1 = *(const bf16x8*)&As[p][w2 * 16 + l16][32 + quad * 8];
        #pragma unroll
        for (int tn = 0; tn < 6; ++tn) {
            bf16x8 b0 = *(const bf16x8*)&Ws[p][grp * 96 + tn * 16 + l16][quad * 8];
            bf16x8 b1 = *(const bf16x8*)&Ws[p][grp * 96 + tn * 16 + l16][32 + quad * 8];
            acc[tn] = MFMA16(a0, b0, acc[tn]);
            acc[tn] = MFMA16(a1, b1, acc[tn]);
        }
        if (it < 15) {
            lwrite((it + 1) & 1);
            __syncthreads();
        }
    }
    // ---- epilogue: stage half-tile fragment-order into dead Ws[0] (6144 shorts).
    // tile = blockIdx>>1, bh = blockIdx&1 (rows bh*32 .. bh*32+31 of the tile).
    const int tile = blockIdx.x >> 1, bh = blockIdx.x & 1;
    short* stage = &Ws[0][0][0];
    #pragma unroll
    for (int tn = 0; tn < 6; ++tn) {
        int gc = grp * 96 + tn * 16 + l16;
        int mat = gc >> 6, h = gc & 63;
        const float* bias = (mat == 0) ? bk : (mat == 1) ? bq : bv;
        float bb = bias[h];
        float sc = (mat == 0) ? KSCALE : 1.f;
        #pragma unroll
        for (int r = 0; r < 4; ++r) {
            int s = w2 * 16 + quad * 4 + r;          // row within 32-half [0,32)
            short val = f2bf((acc[tn][r] + bb) * sc);
            int o;
            if (mat == 2) {
                // V local: hn*512 + ((s>>3)*16 + (h&15))*8 + (s&7)  in [0,2048)
                o = 4096 + (h >> 4) * 512 + (((s >> 3) * 16) + (h & 15)) * 8 + (s & 7);
            } else {
                // K/Q local: (s>>4)*1024 + (h>>5)*512 + (((h&31)>>3)*16 + (s&15))*8 + (h&7)
                o = mat * 2048 + (s >> 4) * 1024 + (h >> 5) * 512
                    + ((((h & 31) >> 3) * 16) + (s & 15)) * 8 + (h & 7);
            }
            stage[o] = val;
        }
    }
    __syncthreads();
    // coalesced copy: K half [0,2048) -> Kf[tile*4096 + bh*2048 + .];
    // Q half [2048,4096) -> Qf likewise; V [4096,6144): run u in hn-block ->
    // Vf[tile*4096 + hn*1024 + bh*512 + u].
    {
        int voff = tid * 8;                          // [0,2048)
        *(bf16x8*)&Kf[(size_t)tile * 4096 + bh * 2048 + voff] =
            *(const bf16x8*)&stage[voff];
        *(bf16x8*)&Qf[(size_t)tile * 4096 + bh * 2048 + voff] =
            *(const bf16x8*)&stage[2048 + voff];
        int hn = tid >> 6, u = voff & 511;           // 4 runs of 512
        *(bf16x8*)&Vf[(size_t)tile * 4096 + hn * 1024 + bh * 512 + u] =
            *(const bf16x8*)&stage[4096 + voff];
    }
}

// ---------------------------------------------------------------------------
// Kernel 3: flash attention partial, software-pipelined, XCD-locality remapped.
// blockIdx%8 = target XCD x; b = x>>1; x&1 selects chunk-offset set {0,1,6,7}
// (64+56+16+8=144) or {2,3,4,5} (48+40+32+24=144) — 144 blocks/XCD exact.
// Fragment-native K/Q/V loads. 4 waves/block; wave = (sh, sp). NO ATOMICS/FENCES.
// ---------------------------------------------------------------------------
__global__ __launch_bounds__(256) void attn_part_kernel(
    const short* __restrict__ Kf, const short* __restrict__ Qf,
    const short* __restrict__ Vf, float* __restrict__ Pb,
    float* __restrict__ lnPb)
{
    __shared__ short Pl[4][2][16][76];         // [wave][strip][t16][s]
    __shared__ float Ob[64][68];               // merge buffer (16B-aligned rows)
    __shared__ float lnb[64];
    const int tid = threadIdx.x;
    const int wv = tid >> 6, lane = tid & 63;
    const int quad = lane >> 4, l16 = lane & 15;
    const int sp = wv & 1, sh = wv >> 1;       // strip-pair, s-half
    const int g = blockIdx.x;                  // 0..1151
    const int x = g & 7;                       // target XCD (blockIdx%8 heuristic)
    const int i = g >> 3;                      // 0..143 within XCD
    const int b = x >> 1;                      // one batch per XCD pair
    int tt, chi;
    if ((x & 1) == 0) {                        // chunk-offsets {0,1,6,7}
        if (i < 64)       { chi = 0; tt = i; }
        else if (i < 120) { chi = 1; tt = 8 + (i - 64); }
        else if (i < 136) { chi = 6; tt = 48 + (i - 120); }
        else              { chi = 7; tt = 56 + (i - 136); }
    } else {                                   // chunk-offsets {2,3,4,5}
        if (i < 48)       { chi = 2; tt = 16 + i; }
        else if (i < 88)  { chi = 3; tt = 24 + (i - 48); }
        else if (i < 120) { chi = 4; tt = 32 + (i - 88); }
        else              { chi = 5; tt = 40 + (i - 120); }
    }
    const int kch = tt / 8 + 1;                // chunks for this tile
    const int c = 4 * kch * (kch - 1) + (tt - 8 * (kch - 1)) * kch + chi;
    const int sA = sp * 2, sB = sp * 2 + 1;    // this wave's two strips (t-sub16s)
    const int st0 = chi * 8;
    const int st1 = min(st0 + 8, tt + 1);

    // K fragments: contiguous 1KB bursts at lane*8 shorts
    const short* kt = Kf + (size_t)(b * 64 + tt) * 4096 + lane * 8;
    bf16x8 kf0a = *(const bf16x8*)(kt + sA * 1024);
    bf16x8 kf1a = *(const bf16x8*)(kt + sA * 1024 + 512);
    bf16x8 kf0b = *(const bf16x8*)(kt + sB * 1024);
    bf16x8 kf1b = *(const bf16x8*)(kt + sB * 1024 + 512);

    bf16x8 ones;
    #pragma unroll
    for (int j = 0; j < 8; ++j) ones[j] = (short)0x3F80;   // bf16 1.0

    f32x4 oA[4], oB[4], lnA, lnB;
    #pragma unroll
    for (int i2 = 0; i2 < 4; ++i2)
        for (int j = 0; j < 4; ++j) { oA[i2][j] = 0.f; oB[i2][j] = 0.f; }
    #pragma unroll
    for (int j = 0; j < 4; ++j) { lnA[j] = 0.f; lnB[j] = 0.f; }

    // this wave's s-tiles: st0+sh, st0+sh+2, ... (interleaved for balance)
    const int myb = st0 + sh;
    const short* qp = Qf + (size_t)(b * 64 + myb) * 4096 + lane * 8;
    const short* vp = Vf + (size_t)(b * 64 + myb) * 4096 + lane * 8;

    bf16x8 qc0[4], qc1[4];
    f32x4 sAc[4], sBc[4];
    // prologue: Q(myb) + S(myb)
    if (myb < st1) {
        #pragma unroll
        for (int tn = 0; tn < 4; ++tn) {
            qc0[tn] = *(const bf16x8*)(qp + tn * 1024);
            qc1[tn] = *(const bf16x8*)(qp + tn * 1024 + 512);
        }
        __builtin_amdgcn_s_setprio(1);
        #pragma unroll
        for (int tn = 0; tn < 4; ++tn) {
            #pragma unroll
            for (int j = 0; j < 4; ++j) { sAc[tn][j] = 0.f; sBc[tn][j] = 0.f; }
            sAc[tn] = MFMA16(qc0[tn], kf0a, sAc[tn]);
            sAc[tn] = MFMA16(qc1[tn], kf1a, sAc[tn]);
            sBc[tn] = MFMA16(qc0[tn], kf0b, sBc[tn]);
            sBc[tn] = MFMA16(qc1[tn], kf1b, sBc[tn]);
        }
        __builtin_amdgcn_s_setprio(0);
    }

    for (int st = myb; st < st1; st += 2) {
        // V(st) fragments (consumed by PV at the end)
        bf16x8 vb0[4], vb1[4];
        #pragma unroll
        for (int hn = 0; hn < 4; ++hn) {
            vb0[hn] = *(const bf16x8*)(vp + hn * 1024);
            vb1[hn] = *(const bf16x8*)(vp + hn * 1024 + 512);
        }
        // Q(st+2) load, issued early — covered by exp/pack below
        const size_t qoff = (st + 2 < st1) ? 8192 : 0;
        #pragma unroll
        for (int tn = 0; tn < 4; ++tn) {
            qc0[tn] = *(const bf16x8*)(qp + qoff + tn * 1024);
            qc1[tn] = *(const bf16x8*)(qp + qoff + tn * 1024 + 512);
        }
        // exp/pack(st) — consumes sAc/sBc (computed last iteration)
        const bool diag = (st == tt);
        #pragma unroll
        for (int tn = 0; tn < 4; ++tn) {
            bf16x4 pa, pb;
            #pragma unroll
            for (int r = 0; r < 4; ++r) {
                float va = sAc[tn][r], vb = sBc[tn][r];
                if (diag) {
                    int scol = tn * 16 + quad * 4 + r;
                    if (scol > sA * 16 + l16) va = -INFINITY;
                    if (scol > sB * 16 + l16) vb = -INFINITY;
                }
                pa[r] = f2bf(fexp2(va));
                pb[r] = f2bf(fexp2(vb));
            }
            *(bf16x4*)&Pl[wv][0][l16][tn * 16 + quad * 4] = pa;
            *(bf16x4*)&Pl[wv][1][l16][tn * 16 + quad * 4] = pb;
        }
        // P read-back (LDS); latency hidden by the S-MFMA cluster below
        bf16x8 aA0 = *(const bf16x8*)&Pl[wv][0][l16][quad * 8];
        bf16x8 aA1 = *(const bf16x8*)&Pl[wv][0][l16][32 + quad * 8];
        bf16x8 aB0 = *(const bf16x8*)&Pl[wv][1][l16][quad * 8];
        bf16x8 aB1 = *(const bf16x8*)&Pl[wv][1][l16][32 + quad * 8];
        // S-MFMA for st+2 (independent of P; sAc/sBc reused after exp)
        if (st + 2 < st1) {
            __builtin_amdgcn_s_setprio(1);
            #pragma unroll
            for (int tn = 0; tn < 4; ++tn) {
                #pragma unroll
                for (int j = 0; j < 4; ++j) { sAc[tn][j] = 0.f; sBc[tn][j] = 0.f; }
                sAc[tn] = MFMA16(qc0[tn], kf0a, sAc[tn]);
                sAc[tn] = MFMA16(qc1[tn], kf1a, sAc[tn]);
                sBc[tn] = MFMA16(qc0[tn], kf0b, sBc[tn]);
                sBc[tn] = MFMA16(qc1[tn], kf1b, sBc[tn]);
            }
            __builtin_amdgcn_s_setprio(0);
        }
        // PV(st) for both strips
        __builtin_amdgcn_s_setprio(1);
        #pragma unroll
        for (int hn = 0; hn < 4; ++hn) {
            oA[hn] = MFMA16(aA0, vb0[hn], oA[hn]);
            oA[hn] = MFMA16(aA1, vb1[hn], oA[hn]);
            oB[hn] = MFMA16(aB0, vb0[hn], oB[hn]);
            oB[hn] = MFMA16(aB1, vb1[hn], oB[hn]);
        }
        lnA = MFMA16(aA0, ones, lnA);
        lnA = MFMA16(aA1, ones, lnA);
        lnB = MFMA16(aB0, ones, lnB);
        lnB = MFMA16(aB1, ones, lnB);
        __builtin_amdgcn_s_setprio(0);
        qp += 8192;
        vp += 8192;
    }

    // s-half merge: sh==1 stages partials; sh==0 adds, writes sums back to Ob;
    // then ALL waves store the 64x64 slab as coalesced float4.
    const int rbase = sp * 32;
    if (sh == 1) {
        #pragma unroll
        for (int hn = 0; hn < 4; ++hn)
            #pragma unroll
            for (int r = 0; r < 4; ++r) {
                Ob[rbase + quad * 4 + r][hn * 16 + l16] = oA[hn][r];
                Ob[rbase + 16 + quad * 4 + r][hn * 16 + l16] = oB[hn][r];
            }
        if (l16 == 0) {
            #pragma unroll
            for (int r = 0; r < 4; ++r) {
                lnb[rbase + quad * 4 + r] = lnA[r];
                lnb[rbase + 16 + quad * 4 + r] = lnB[r];
            }
        }
    }
    __syncthreads();
    if (sh == 0) {
        #pragma unroll
        for (int hn = 0; hn < 4; ++hn)
            #pragma unroll
            for (int r = 0; r < 4; ++r) {
                int ra = rbase + quad * 4 + r;
                int rb = ra + 16;
                Ob[ra][hn * 16 + l16] += oA[hn][r];
                Ob[rb][hn * 16 + l16] += oB[hn][r];
            }
        if (l16 == 0) {
            float* lc = lnPb + (size_t)(b * CPB + c) * 64;
            #pragma unroll
            for (int r = 0; r < 4; ++r) {
                lc[rbase + quad * 4 + r] = lnA[r] + lnb[rbase + quad * 4 + r];
                lc[rbase + 16 + quad * 4 + r] = lnB[r] + lnb[rbase + 16 + quad * 4 + r];
            }
        }
    }
    __syncthreads();
    float4* Pc4 = (float4*)(Pb + (size_t)(b * CPB + c) * 4096);
    #pragma unroll
    for (int i2 = 0; i2 < 4; ++i2) {
        int idx = tid + i2 * 256;                  // 0..1023 float4 index
        int row = idx >> 4, c4 = (idx & 15) * 4;
        Pc4[idx] = *(const float4*)&Ob[row][c4];
    }
}

// ---------------------------------------------------------------------------
// Kernel 4: reduce <=8 contiguous chunk partials per t-tile, normalize, write out.
// Grid: BATCH*64 blocks of 256 threads.
// ---------------------------------------------------------------------------
__global__ __launch_bounds__(256) void reduce_norm_kernel(
    const float* __restrict__ Pb, const float* __restrict__ lnPb,
    float* __restrict__ out)
{
    const int blk = blockIdx.x;                // b*64 + tt
    const int b = blk >> 6, tt = blk & 63;
    const int k = tt / 8 + 1;                  // number of chunk partials
    const int base_c = 4 * k * (k - 1) + (tt - 8 * (k - 1)) * k;
    const int tid = threadIdx.x;
    __shared__ float lnS[64];
    if (tid < 64) {
        float s = 0.f;
        for (int i = 0; i < k; ++i)
            s += lnPb[(size_t)(b * CPB + base_c + i) * 64 + tid];
        lnS[tid] = 1.f / s;
    }
    __syncthreads();
    float4 acc[4];
    #pragma unroll
    for (int j = 0; j < 4; ++j) acc[j] = {0.f, 0.f, 0.f, 0.f};
    for (int i = 0; i < k; ++i) {
        const float4* p4 = (const float4*)(Pb + (size_t)(b * CPB + base_c + i) * 4096);
        #pragma unroll
        for (int j = 0; j < 4; ++j) {
            float4 v = p4[tid + j * 256];
            acc[j].x += v.x; acc[j].y += v.y; acc[j].z += v.z; acc[j].w += v.w;
        }
    }
    float4* o4 = (float4*)out;
    const size_t obase = ((size_t)b * T + (size_t)tt * 64) * 16;   // float4 units
    #pragma unroll
    for (int j = 0; j < 4; ++j) {
        int idx = tid + j * 256;               // float4 index within 64x64 tile
        float inv = lnS[idx >> 4];             // 16 float4 per row
        float4 v = acc[j];
        v.x *= inv; v.y *= inv; v.z *= inv; v.w *= inv;
        o4[obase + idx] = v;
    }
}

// ---------------------------------------------------------------------------
extern "C" void kernel_launch(void* const* d_in, const int* in_sizes, int n_in,
                              void* d_out, int out_size, void* d_ws, size_t ws_size,
                              hipStream_t stream) {
    const float* x  = (const float*)d_in[0];
    const float* Wk = (const float*)d_in[1];
    const float* bk = (const float*)d_in[2];
    const float* Wq = (const float*)d_in[3];
    const float* bq = (const float*)d_in[4];
    const float* Wv = (const float*)d_in[5];
    const float* bv = (const float*)d_in[6];
    float* out = (float*)d_out;

    char* ws = (char*)d_ws;
    size_t off = 0;
    short* Kf   = (short*)(ws + off); off += (size_t)M * H * 2;            // 2 MB
    short* Qf   = (short*)(ws + off); off += (size_t)M * H * 2;            // 2 MB
    short* Vf   = (short*)(ws + off); off += (size_t)M * H * 2;            // 2 MB
    short* Wt_g = (short*)(ws + off); off += (size_t)192 * C * 2;          // 384 KB
    float* Pb   = (float*)(ws + off); off += (size_t)BATCH * CPB * 4096 * 4; // 18.9 MB
    float* lnPb = (float*)(ws + off); off += (size_t)BATCH * CPB * 64 * 4;   // 295 KB
    // total ~25.6 MB

    wtrans_kernel<<<48, 256, 0, stream>>>(Wk, Wq, Wv, Wt_g);
    proj_kernel<<<M / 32, 256, 0, stream>>>(x, Wt_g, bk, bq, bv, Kf, Qf, Vf);
    attn_part_kernel<<<BATCH * CPB, 256, 0, stream>>>(Kf, Qf, Vf, Pb, lnPb);
    reduce_norm_kernel<<<BATCH * 64, 256, 0, stream>>>(Pb, lnPb, out);
}